// Round 13
// baseline (106.129 us; speedup 1.0000x reference)
//
#include <hip/hip_runtime.h>

#define B_  2
#define TQ  1024
#define TV  1024
#define DD  512
#define UU  128

#define QB  4            // q-rows per fused block

typedef __attribute__((ext_vector_type(8))) short short8;
typedef __attribute__((ext_vector_type(4))) float f32x4;

__device__ __forceinline__ unsigned short f2bf(float x){
    unsigned int u = __float_as_uint(x);
    unsigned int r = (u + 0x7FFFu + ((u >> 16) & 1u)) >> 16;
    return (unsigned short)r;
}
__device__ __forceinline__ float bf2f(unsigned short h){
    return __uint_as_float(((unsigned int)h) << 16);
}

// ---------------- prep: proj (+exp2) and vsplit merged ----------------
// blocks [0,1024): proj 4 rows each -> EQ/EK = exp2(C * X@W)
// blocks [1024,1280): vsplit: value [b][k][d] -> vht/vlt [b][d][k] bf16 h/l planes
__global__ __launch_bounds__(256)
void prep_kernel(const float* __restrict__ query, const float* __restrict__ value,
                 const float* __restrict__ W1,    const float* __restrict__ W2,
                 float* __restrict__ eq, float* __restrict__ ek,
                 unsigned short* __restrict__ vht, unsigned short* __restrict__ vlt){
    __shared__ float t[64][65];
    const int bid = blockIdx.x;
    const int tid = threadIdx.x;

    if (bid < 1024){
        const float TWO_LOG2E = 2.8853900817779268f;
        const int qk   = bid >> 9;
        const int b    = (bid >> 8) & 1;
        const int tblk = bid & 255;
        const float* X = qk ? value : query;
        const float* W = qk ? W2    : W1;
        float* out     = qk ? ek    : eq;

        const int u    = tid & 127;
        const int half = tid >> 7;
        const int t0   = tblk * 4 + half * 2;
        const float* x = X + ((size_t)b * TQ + t0) * DD;

        float acc0 = 0.f, acc1 = 0.f;
        for (int d = 0; d < DD; d += 4){
            float w0 = W[(d+0)*UU + u];
            float w1 = W[(d+1)*UU + u];
            float w2 = W[(d+2)*UU + u];
            float w3 = W[(d+3)*UU + u];
            float4 x0 = *reinterpret_cast<const float4*>(x + 0*DD + d);
            float4 x1 = *reinterpret_cast<const float4*>(x + 1*DD + d);
            acc0 = fmaf(x0.x,w0,acc0); acc0 = fmaf(x0.y,w1,acc0); acc0 = fmaf(x0.z,w2,acc0); acc0 = fmaf(x0.w,w3,acc0);
            acc1 = fmaf(x1.x,w0,acc1); acc1 = fmaf(x1.y,w1,acc1); acc1 = fmaf(x1.z,w2,acc1); acc1 = fmaf(x1.w,w3,acc1);
        }
        size_t o = ((size_t)b * TQ + t0) * UU + u;
        out[o + 0*UU] = __builtin_amdgcn_exp2f(TWO_LOG2E * acc0);
        out[o + 1*UU] = __builtin_amdgcn_exp2f(TWO_LOG2E * acc1);
    } else {
        const int vb  = bid - 1024;
        const int b   = vb >> 7;
        const int rem = vb & 127;
        const int k0  = (rem >> 3) * 64;
        const int d0  = (rem & 7) * 64;

        #pragma unroll
        for (int i = 0; i < 4; ++i){
            int r = (tid >> 4) + 16*i;
            int c = (tid & 15) * 4;
            float4 v = *reinterpret_cast<const float4*>(value + ((size_t)b*TV + k0 + r)*DD + d0 + c);
            t[r][c+0]=v.x; t[r][c+1]=v.y; t[r][c+2]=v.z; t[r][c+3]=v.w;
        }
        __syncthreads();

        const int dr = tid >> 2;
        const int kc = (tid & 3) * 16;
        #pragma unroll
        for (int g = 0; g < 2; ++g){
            unsigned short h8[8], l8[8];
            #pragma unroll
            for (int e = 0; e < 8; ++e){
                float v = t[kc + g*8 + e][dr];
                unsigned short h = f2bf(v);
                h8[e] = h; l8[e] = f2bf(v - bf2f(h));
            }
            size_t o = ((size_t)b*DD + d0 + dr)*TV + k0 + kc + g*8;
            *reinterpret_cast<int4*>(vht + o) = *reinterpret_cast<const int4*>(h8);
            *reinterpret_cast<int4*>(vlt + o) = *reinterpret_cast<const int4*>(l8);
        }
    }
}

// ---------------- fused scores + softmax (UNCHANGED from r11/r12) ----------------
__global__ __launch_bounds__(1024, 8)
void fused_kernel(const float* __restrict__ eq, const float* __restrict__ ek,
                  const float* __restrict__ scale, float* __restrict__ attn){
    __shared__ float qs[QB][UU];
    __shared__ float sc[UU];
    __shared__ float sm[QB][TV];
    __shared__ float pmax[QB][4];
    __shared__ float psum[QB][4];

    const float LOG2E = 1.4426950408889634f;
    const int b   = blockIdx.y;
    const int q0  = blockIdx.x * QB;
    const int tid = threadIdx.x;
    const int w   = tid >> 6, lane = tid & 63;

    if (tid < QB*UU)
        qs[tid >> 7][tid & 127] = eq[((size_t)b * TQ + q0 + (tid >> 7)) * UU + (tid & 127)];
    if (tid < UU)
        sc[tid] = -2.0f * scale[tid];
    __syncthreads();

    const float4* ekv = reinterpret_cast<const float4*>(ek + (size_t)b * TV * UU);
    const float4* qs4 = reinterpret_cast<const float4*>(&qs[0][0]);
    const float4* sc4 = reinterpret_cast<const float4*>(&sc[0]);

    const int kA = w*64 + lane;
    const size_t iA = (size_t)kA * 32;

    float acc[QB] = {};
    float4 kva = ekv[iA];

    for (int j = 0; j < 32; ++j){
        float4 nka;
        if (j != 31) nka = ekv[iA + j + 1];
        float4 s4 = sc4[j];
        #pragma unroll
        for (int r = 0; r < QB; ++r){
            float4 q4 = qs4[r*32 + j];
            acc[r] = fmaf(s4.x, __builtin_amdgcn_rcpf(fmaf(q4.x, kva.x, 1.0f)), acc[r]);
            acc[r] = fmaf(s4.y, __builtin_amdgcn_rcpf(fmaf(q4.y, kva.y, 1.0f)), acc[r]);
            acc[r] = fmaf(s4.z, __builtin_amdgcn_rcpf(fmaf(q4.z, kva.z, 1.0f)), acc[r]);
            acc[r] = fmaf(s4.w, __builtin_amdgcn_rcpf(fmaf(q4.w, kva.w, 1.0f)), acc[r]);
        }
        kva = nka;
    }

    #pragma unroll
    for (int r = 0; r < QB; ++r) sm[r][kA] = acc[r];
    __syncthreads();

    {
        const int r   = w & 3;
        const int seg = w >> 2;
        float s[4];
        #pragma unroll
        for (int t = 0; t < 4; ++t) s[t] = sm[r][seg*256 + t*64 + lane];

        float m = fmaxf(fmaxf(s[0], s[1]), fmaxf(s[2], s[3]));
        #pragma unroll
        for (int off = 32; off >= 1; off >>= 1) m = fmaxf(m, __shfl_xor(m, off, 64));
        if (lane == 0) pmax[r][seg] = m;
        __syncthreads();

        float M = fmaxf(fmaxf(pmax[r][0], pmax[r][1]), fmaxf(pmax[r][2], pmax[r][3]));
        float sum = 0.f;
        #pragma unroll
        for (int t = 0; t < 4; ++t){ s[t] = __builtin_amdgcn_exp2f((s[t] - M) * LOG2E); sum += s[t]; }
        #pragma unroll
        for (int off = 32; off >= 1; off >>= 1) sum += __shfl_xor(sum, off, 64);
        if (lane == 0) psum[r][seg] = sum;
        __syncthreads();

        float S = (psum[r][0] + psum[r][1]) + (psum[r][2] + psum[r][3]);
        float inv = 1.0f / S;

        float* arow = attn + ((size_t)b * TQ + q0 + r) * TV + seg*256;
        #pragma unroll
        for (int t = 0; t < 4; ++t) arow[t*64 + lane] = s[t] * inv;
    }
}

// ---------------- context = attn @ value via bf16-split MFMA ----------------
// Tile 32x64, K-step 64, 4 waves (1m x 4n), 512 blocks = 2 blocks/CU.
__global__ __launch_bounds__(256, 2)
void ctx_kernel(const float* __restrict__ attn,
                const unsigned short* __restrict__ vht, const unsigned short* __restrict__ vlt,
                float* __restrict__ ctx){
    __shared__ unsigned short Ah[32*64], Al[32*64], Vh[64*64], Vl[64*64];

    const int m0   = blockIdx.x * 32;
    const int n0   = blockIdx.y * 64;
    const int b    = m0 >> 10;
    const int tid  = threadIdx.x;
    const int lane = tid & 63;
    const int w    = tid >> 6;

    // A staging: row am (0..31), k-chunk kq (8 elems); V: col cn (0..63), k-chunk kv (16)
    const int am = tid >> 3;
    const int kq = (tid & 7) * 8;
    const int cn = tid >> 2;
    const int kv = (tid & 3) * 16;

    const float*          arow  = attn + (size_t)(m0 + am) * TV;
    const unsigned short* vhrow = vht + ((size_t)b * DD + n0 + cn) * TV;
    const unsigned short* vlrow = vlt + ((size_t)b * DD + n0 + cn) * TV;

    float ra[8];
    int4 rvh0, rvh1, rvl0, rvl1;
    #pragma unroll
    for (int i = 0; i < 2; ++i)
        *reinterpret_cast<float4*>(&ra[i*4]) = *reinterpret_cast<const float4*>(arow + kq + i*4);
    rvh0 = *reinterpret_cast<const int4*>(vhrow + kv);
    rvh1 = *reinterpret_cast<const int4*>(vhrow + kv + 8);
    rvl0 = *reinterpret_cast<const int4*>(vlrow + kv);
    rvl1 = *reinterpret_cast<const int4*>(vlrow + kv + 8);

    f32x4 acc[2];
    acc[0] = (f32x4){0.f,0.f,0.f,0.f};
    acc[1] = (f32x4){0.f,0.f,0.f,0.f};

    const int ga  = (kq >> 3) ^ (am & 7);               // A chunk group (1 per thread)
    const int gv0 = ((kv >> 3) + 0) ^ (cn & 7);         // V chunk groups (2 per thread)
    const int gv1 = ((kv >> 3) + 1) ^ (cn & 7);

    for (int kt = 0; kt < TV; kt += 64){
        {
            unsigned short h8[8], l8[8];
            #pragma unroll
            for (int e = 0; e < 8; ++e){
                float a = ra[e];
                unsigned short h = f2bf(a);
                h8[e] = h; l8[e] = f2bf(a - bf2f(h));
            }
            *reinterpret_cast<int4*>(&Ah[am*64 + ga*8]) = *reinterpret_cast<const int4*>(h8);
            *reinterpret_cast<int4*>(&Al[am*64 + ga*8]) = *reinterpret_cast<const int4*>(l8);
        }
        *reinterpret_cast<int4*>(&Vh[cn*64 + gv0*8]) = rvh0;
        *reinterpret_cast<int4*>(&Vh[cn*64 + gv1*8]) = rvh1;
        *reinterpret_cast<int4*>(&Vl[cn*64 + gv0*8]) = rvl0;
        *reinterpret_cast<int4*>(&Vl[cn*64 + gv1*8]) = rvl1;

        const int ktn = (kt + 64 < TV) ? kt + 64 : 0;
        #pragma unroll
        for (int i = 0; i < 2; ++i)
            *reinterpret_cast<float4*>(&ra[i*4]) = *reinterpret_cast<const float4*>(arow + ktn + kq + i*4);
        rvh0 = *reinterpret_cast<const int4*>(vhrow + ktn + kv);
        rvh1 = *reinterpret_cast<const int4*>(vhrow + ktn + kv + 8);
        rvl0 = *reinterpret_cast<const int4*>(vlrow + ktn + kv);
        rvl1 = *reinterpret_cast<const int4*>(vlrow + ktn + kv + 8);

        __syncthreads();

        #pragma unroll
        for (int kk = 0; kk < 2; ++kk){
            const int kg = kk*4 + (lane >> 4);
            const int g  = (kg ^ (lane & 7)) * 8;
            const int r0 = (lane & 15) * 64;
            const int c0 = (w*16 + (lane & 15)) * 64;

            short8 a0h = *reinterpret_cast<const short8*>(&Ah[r0 + g]);
            short8 a1h = *reinterpret_cast<const short8*>(&Ah[r0 + 16*64 + g]);
            short8 a0l = *reinterpret_cast<const short8*>(&Al[r0 + g]);
            short8 a1l = *reinterpret_cast<const short8*>(&Al[r0 + 16*64 + g]);
            short8 bh  = *reinterpret_cast<const short8*>(&Vh[c0 + g]);
            short8 bl  = *reinterpret_cast<const short8*>(&Vl[c0 + g]);

            acc[0] = __builtin_amdgcn_mfma_f32_16x16x32_bf16(a0h, bh, acc[0], 0, 0, 0);
            acc[0] = __builtin_amdgcn_mfma_f32_16x16x32_bf16(a0l, bh, acc[0], 0, 0, 0);
            acc[0] = __builtin_amdgcn_mfma_f32_16x16x32_bf16(a0h, bl, acc[0], 0, 0, 0);

            acc[1] = __builtin_amdgcn_mfma_f32_16x16x32_bf16(a1h, bh, acc[1], 0, 0, 0);
            acc[1] = __builtin_amdgcn_mfma_f32_16x16x32_bf16(a1l, bh, acc[1], 0, 0, 0);
            acc[1] = __builtin_amdgcn_mfma_f32_16x16x32_bf16(a1h, bl, acc[1], 0, 0, 0);
        }

        __syncthreads();
    }

    #pragma unroll
    for (int fm = 0; fm < 2; ++fm){
        const int row = m0 + fm*16 + (lane >> 4) * 4;
        const int col = n0 + w*16 + (lane & 15);
        #pragma unroll
        for (int r = 0; r < 4; ++r)
            ctx[(size_t)(row + r) * DD + col] = acc[fm][r];
    }
}

extern "C" void kernel_launch(void* const* d_in, const int* in_sizes, int n_in,
                              void* d_out, int out_size, void* d_ws, size_t ws_size,
                              hipStream_t stream){
    const float* query = (const float*)d_in[0];
    const float* value = (const float*)d_in[1];
    const float* W1    = (const float*)d_in[2];
    const float* W2    = (const float*)d_in[3];
    const float* scale = (const float*)d_in[4];

    float* eq = (float*)d_ws;                              // 1 MB
    float* ek = eq + (size_t)B_ * TQ * UU;                 // 1 MB
    unsigned short* vht = (unsigned short*)(ek + (size_t)B_ * TV * UU);   // 2 MB
    unsigned short* vlt = vht + (size_t)B_ * DD * TV;                     // 2 MB

    float* out  = (float*)d_out;
    float* ctx  = out;                                     // [B][TQ][DD]
    float* attn = out + (size_t)B_ * TQ * DD;              // [B][TQ][TV]

    prep_kernel<<<1280, 256, 0, stream>>>(query, value, W1, W2, eq, ek, vht, vlt);
    fused_kernel<<<dim3(TQ/QB, B_), 1024, 0, stream>>>(eq, ek, scale, attn);
    ctx_kernel<<<dim3((B_*TQ)/32, DD/64), 256, 0, stream>>>(attn, vht, vlt, ctx);
}

// Round 14
// 103.329 us; speedup vs baseline: 1.0271x; 1.0271x over previous
//
#include <hip/hip_runtime.h>

#define B_  2
#define TQ  1024
#define TV  1024
#define DD  512
#define UU  128

#define QB  4            // q-rows per fused block

typedef __attribute__((ext_vector_type(8))) short short8;
typedef __attribute__((ext_vector_type(4))) float f32x4;

__device__ __forceinline__ unsigned short f2bf(float x){
    unsigned int u = __float_as_uint(x);
    unsigned int r = (u + 0x7FFFu + ((u >> 16) & 1u)) >> 16;
    return (unsigned short)r;
}
__device__ __forceinline__ float bf2f(unsigned short h){
    return __uint_as_float(((unsigned int)h) << 16);
}

// ---------------- projections + exp2 epilogue, W staged in LDS ----------------
// EQ = exp2(C*query@W1), EK = exp2(C*value@W2), C = 2*log2(e)
// block = 256 thr, 8 rows (4 per half), W k-tile [64][128] in LDS (32 KB).
__global__ __launch_bounds__(256)
void proj_kernel(const float* __restrict__ query, const float* __restrict__ value,
                 const float* __restrict__ W1,    const float* __restrict__ W2,
                 float* __restrict__ eq, float* __restrict__ ek){
    __shared__ float Ws[64 * UU];    // 32 KB
    const float TWO_LOG2E = 2.8853900817779268f;
    const int qk = blockIdx.z;
    const int b  = blockIdx.y;
    const float* X = qk ? value : query;
    const float* W = qk ? W2    : W1;
    float* out     = qk ? ek    : eq;

    const int tid  = threadIdx.x;
    const int u    = tid & 127;
    const int half = tid >> 7;
    const int t0   = blockIdx.x * 8 + half * 4;
    const float* x = X + ((size_t)b * TQ + t0) * DD;

    const int sr = tid >> 5;          // staging row 0..7
    const int sc = (tid & 31) * 4;    // staging col

    float acc0 = 0.f, acc1 = 0.f, acc2 = 0.f, acc3 = 0.f;
    for (int k0 = 0; k0 < DD; k0 += 64){
        __syncthreads();
        #pragma unroll
        for (int i = 0; i < 8; ++i)
            *reinterpret_cast<float4*>(&Ws[(sr + 8*i)*UU + sc]) =
                *reinterpret_cast<const float4*>(W + (size_t)(k0 + sr + 8*i)*UU + sc);
        __syncthreads();

        #pragma unroll 4
        for (int d = 0; d < 64; d += 4){
            float w0 = Ws[(d+0)*UU + u];
            float w1 = Ws[(d+1)*UU + u];
            float w2 = Ws[(d+2)*UU + u];
            float w3 = Ws[(d+3)*UU + u];
            float4 x0 = *reinterpret_cast<const float4*>(x + 0*DD + k0 + d);
            float4 x1 = *reinterpret_cast<const float4*>(x + 1*DD + k0 + d);
            float4 x2 = *reinterpret_cast<const float4*>(x + 2*DD + k0 + d);
            float4 x3 = *reinterpret_cast<const float4*>(x + 3*DD + k0 + d);
            acc0 = fmaf(x0.x,w0,acc0); acc0 = fmaf(x0.y,w1,acc0); acc0 = fmaf(x0.z,w2,acc0); acc0 = fmaf(x0.w,w3,acc0);
            acc1 = fmaf(x1.x,w0,acc1); acc1 = fmaf(x1.y,w1,acc1); acc1 = fmaf(x1.z,w2,acc1); acc1 = fmaf(x1.w,w3,acc1);
            acc2 = fmaf(x2.x,w0,acc2); acc2 = fmaf(x2.y,w1,acc2); acc2 = fmaf(x2.z,w2,acc2); acc2 = fmaf(x2.w,w3,acc2);
            acc3 = fmaf(x3.x,w0,acc3); acc3 = fmaf(x3.y,w1,acc3); acc3 = fmaf(x3.z,w2,acc3); acc3 = fmaf(x3.w,w3,acc3);
        }
    }
    size_t o = ((size_t)b * TQ + t0) * UU + u;
    out[o + 0*UU] = __builtin_amdgcn_exp2f(TWO_LOG2E * acc0);
    out[o + 1*UU] = __builtin_amdgcn_exp2f(TWO_LOG2E * acc1);
    out[o + 2*UU] = __builtin_amdgcn_exp2f(TWO_LOG2E * acc2);
    out[o + 3*UU] = __builtin_amdgcn_exp2f(TWO_LOG2E * acc3);
}

// ---------------- V transpose + bf16 h/l split (one-shot) ----------------
__global__ __launch_bounds__(256)
void vsplit_kernel(const float* __restrict__ value,
                   unsigned short* __restrict__ vht, unsigned short* __restrict__ vlt){
    __shared__ float t[64][65];
    const int b  = blockIdx.z;
    const int k0 = blockIdx.x * 64;
    const int d0 = blockIdx.y * 64;
    const int tid = threadIdx.x;

    #pragma unroll
    for (int i = 0; i < 4; ++i){
        int r = (tid >> 4) + 16*i;
        int c = (tid & 15) * 4;
        float4 v = *reinterpret_cast<const float4*>(value + ((size_t)b*TV + k0 + r)*DD + d0 + c);
        t[r][c+0]=v.x; t[r][c+1]=v.y; t[r][c+2]=v.z; t[r][c+3]=v.w;
    }
    __syncthreads();

    const int dr = tid >> 2;
    const int kc = (tid & 3) * 16;
    #pragma unroll
    for (int g = 0; g < 2; ++g){
        unsigned short h8[8], l8[8];
        #pragma unroll
        for (int e = 0; e < 8; ++e){
            float v = t[kc + g*8 + e][dr];
            unsigned short h = f2bf(v);
            h8[e] = h; l8[e] = f2bf(v - bf2f(h));
        }
        size_t o = ((size_t)b*DD + d0 + dr)*TV + k0 + kc + g*8;
        *reinterpret_cast<int4*>(vht + o) = *reinterpret_cast<const int4*>(h8);
        *reinterpret_cast<int4*>(vlt + o) = *reinterpret_cast<const int4*>(l8);
    }
}

// ---------------- fused scores + softmax (UNCHANGED) ----------------
__global__ __launch_bounds__(1024, 8)
void fused_kernel(const float* __restrict__ eq, const float* __restrict__ ek,
                  const float* __restrict__ scale, float* __restrict__ attn){
    __shared__ float qs[QB][UU];
    __shared__ float sc[UU];
    __shared__ float sm[QB][TV];
    __shared__ float pmax[QB][4];
    __shared__ float psum[QB][4];

    const float LOG2E = 1.4426950408889634f;
    const int b   = blockIdx.y;
    const int q0  = blockIdx.x * QB;
    const int tid = threadIdx.x;
    const int w   = tid >> 6, lane = tid & 63;

    if (tid < QB*UU)
        qs[tid >> 7][tid & 127] = eq[((size_t)b * TQ + q0 + (tid >> 7)) * UU + (tid & 127)];
    if (tid < UU)
        sc[tid] = -2.0f * scale[tid];
    __syncthreads();

    const float4* ekv = reinterpret_cast<const float4*>(ek + (size_t)b * TV * UU);
    const float4* qs4 = reinterpret_cast<const float4*>(&qs[0][0]);
    const float4* sc4 = reinterpret_cast<const float4*>(&sc[0]);

    const int kA = w*64 + lane;
    const size_t iA = (size_t)kA * 32;

    float acc[QB] = {};
    float4 kva = ekv[iA];

    for (int j = 0; j < 32; ++j){
        float4 nka;
        if (j != 31) nka = ekv[iA + j + 1];
        float4 s4 = sc4[j];
        #pragma unroll
        for (int r = 0; r < QB; ++r){
            float4 q4 = qs4[r*32 + j];
            acc[r] = fmaf(s4.x, __builtin_amdgcn_rcpf(fmaf(q4.x, kva.x, 1.0f)), acc[r]);
            acc[r] = fmaf(s4.y, __builtin_amdgcn_rcpf(fmaf(q4.y, kva.y, 1.0f)), acc[r]);
            acc[r] = fmaf(s4.z, __builtin_amdgcn_rcpf(fmaf(q4.z, kva.z, 1.0f)), acc[r]);
            acc[r] = fmaf(s4.w, __builtin_amdgcn_rcpf(fmaf(q4.w, kva.w, 1.0f)), acc[r]);
        }
        kva = nka;
    }

    #pragma unroll
    for (int r = 0; r < QB; ++r) sm[r][kA] = acc[r];
    __syncthreads();

    {
        const int r   = w & 3;
        const int seg = w >> 2;
        float s[4];
        #pragma unroll
        for (int t = 0; t < 4; ++t) s[t] = sm[r][seg*256 + t*64 + lane];

        float m = fmaxf(fmaxf(s[0], s[1]), fmaxf(s[2], s[3]));
        #pragma unroll
        for (int off = 32; off >= 1; off >>= 1) m = fmaxf(m, __shfl_xor(m, off, 64));
        if (lane == 0) pmax[r][seg] = m;
        __syncthreads();

        float M = fmaxf(fmaxf(pmax[r][0], pmax[r][1]), fmaxf(pmax[r][2], pmax[r][3]));
        float sum = 0.f;
        #pragma unroll
        for (int t = 0; t < 4; ++t){ s[t] = __builtin_amdgcn_exp2f((s[t] - M) * LOG2E); sum += s[t]; }
        #pragma unroll
        for (int off = 32; off >= 1; off >>= 1) sum += __shfl_xor(sum, off, 64);
        if (lane == 0) psum[r][seg] = sum;
        __syncthreads();

        float S = (psum[r][0] + psum[r][1]) + (psum[r][2] + psum[r][3]);
        float inv = 1.0f / S;

        float* arow = attn + ((size_t)b * TQ + q0 + r) * TV + seg*256;
        #pragma unroll
        for (int t = 0; t < 4; ++t) arow[t*64 + lane] = s[t] * inv;
    }
}

// ---------------- context = attn @ value via bf16-split MFMA (UNCHANGED) ----------------
__global__ __launch_bounds__(256, 2)
void ctx_kernel(const float* __restrict__ attn,
                const unsigned short* __restrict__ vht, const unsigned short* __restrict__ vlt,
                float* __restrict__ ctx){
    __shared__ unsigned short Ah[32*64], Al[32*64], Vh[64*64], Vl[64*64];

    const int m0   = blockIdx.x * 32;
    const int n0   = blockIdx.y * 64;
    const int b    = m0 >> 10;
    const int tid  = threadIdx.x;
    const int lane = tid & 63;
    const int w    = tid >> 6;

    const int am = tid >> 3;
    const int kq = (tid & 7) * 8;
    const int cn = tid >> 2;
    const int kv = (tid & 3) * 16;

    const float*          arow  = attn + (size_t)(m0 + am) * TV;
    const unsigned short* vhrow = vht + ((size_t)b * DD + n0 + cn) * TV;
    const unsigned short* vlrow = vlt + ((size_t)b * DD + n0 + cn) * TV;

    float ra[8];
    int4 rvh0, rvh1, rvl0, rvl1;
    #pragma unroll
    for (int i = 0; i < 2; ++i)
        *reinterpret_cast<float4*>(&ra[i*4]) = *reinterpret_cast<const float4*>(arow + kq + i*4);
    rvh0 = *reinterpret_cast<const int4*>(vhrow + kv);
    rvh1 = *reinterpret_cast<const int4*>(vhrow + kv + 8);
    rvl0 = *reinterpret_cast<const int4*>(vlrow + kv);
    rvl1 = *reinterpret_cast<const int4*>(vlrow + kv + 8);

    f32x4 acc[2];
    acc[0] = (f32x4){0.f,0.f,0.f,0.f};
    acc[1] = (f32x4){0.f,0.f,0.f,0.f};

    const int ga  = (kq >> 3) ^ (am & 7);
    const int gv0 = ((kv >> 3) + 0) ^ (cn & 7);
    const int gv1 = ((kv >> 3) + 1) ^ (cn & 7);

    for (int kt = 0; kt < TV; kt += 64){
        {
            unsigned short h8[8], l8[8];
            #pragma unroll
            for (int e = 0; e < 8; ++e){
                float a = ra[e];
                unsigned short h = f2bf(a);
                h8[e] = h; l8[e] = f2bf(a - bf2f(h));
            }
            *reinterpret_cast<int4*>(&Ah[am*64 + ga*8]) = *reinterpret_cast<const int4*>(h8);
            *reinterpret_cast<int4*>(&Al[am*64 + ga*8]) = *reinterpret_cast<const int4*>(l8);
        }
        *reinterpret_cast<int4*>(&Vh[cn*64 + gv0*8]) = rvh0;
        *reinterpret_cast<int4*>(&Vh[cn*64 + gv1*8]) = rvh1;
        *reinterpret_cast<int4*>(&Vl[cn*64 + gv0*8]) = rvl0;
        *reinterpret_cast<int4*>(&Vl[cn*64 + gv1*8]) = rvl1;

        const int ktn = (kt + 64 < TV) ? kt + 64 : 0;
        #pragma unroll
        for (int i = 0; i < 2; ++i)
            *reinterpret_cast<float4*>(&ra[i*4]) = *reinterpret_cast<const float4*>(arow + ktn + kq + i*4);
        rvh0 = *reinterpret_cast<const int4*>(vhrow + ktn + kv);
        rvh1 = *reinterpret_cast<const int4*>(vhrow + ktn + kv + 8);
        rvl0 = *reinterpret_cast<const int4*>(vlrow + ktn + kv);
        rvl1 = *reinterpret_cast<const int4*>(vlrow + ktn + kv + 8);

        __syncthreads();

        #pragma unroll
        for (int kk = 0; kk < 2; ++kk){
            const int kg = kk*4 + (lane >> 4);
            const int g  = (kg ^ (lane & 7)) * 8;
            const int r0 = (lane & 15) * 64;
            const int c0 = (w*16 + (lane & 15)) * 64;

            short8 a0h = *reinterpret_cast<const short8*>(&Ah[r0 + g]);
            short8 a1h = *reinterpret_cast<const short8*>(&Ah[r0 + 16*64 + g]);
            short8 a0l = *reinterpret_cast<const short8*>(&Al[r0 + g]);
            short8 a1l = *reinterpret_cast<const short8*>(&Al[r0 + 16*64 + g]);
            short8 bh  = *reinterpret_cast<const short8*>(&Vh[c0 + g]);
            short8 bl  = *reinterpret_cast<const short8*>(&Vl[c0 + g]);

            acc[0] = __builtin_amdgcn_mfma_f32_16x16x32_bf16(a0h, bh, acc[0], 0, 0, 0);
            acc[0] = __builtin_amdgcn_mfma_f32_16x16x32_bf16(a0l, bh, acc[0], 0, 0, 0);
            acc[0] = __builtin_amdgcn_mfma_f32_16x16x32_bf16(a0h, bl, acc[0], 0, 0, 0);

            acc[1] = __builtin_amdgcn_mfma_f32_16x16x32_bf16(a1h, bh, acc[1], 0, 0, 0);
            acc[1] = __builtin_amdgcn_mfma_f32_16x16x32_bf16(a1l, bh, acc[1], 0, 0, 0);
            acc[1] = __builtin_amdgcn_mfma_f32_16x16x32_bf16(a1h, bl, acc[1], 0, 0, 0);
        }

        __syncthreads();
    }

    #pragma unroll
    for (int fm = 0; fm < 2; ++fm){
        const int row = m0 + fm*16 + (lane >> 4) * 4;
        const int col = n0 + w*16 + (lane & 15);
        #pragma unroll
        for (int r = 0; r < 4; ++r)
            ctx[(size_t)(row + r) * DD + col] = acc[fm][r];
    }
}

extern "C" void kernel_launch(void* const* d_in, const int* in_sizes, int n_in,
                              void* d_out, int out_size, void* d_ws, size_t ws_size,
                              hipStream_t stream){
    const float* query = (const float*)d_in[0];
    const float* value = (const float*)d_in[1];
    const float* W1    = (const float*)d_in[2];
    const float* W2    = (const float*)d_in[3];
    const float* scale = (const float*)d_in[4];

    float* eq = (float*)d_ws;                              // 1 MB
    float* ek = eq + (size_t)B_ * TQ * UU;                 // 1 MB
    unsigned short* vht = (unsigned short*)(ek + (size_t)B_ * TV * UU);   // 2 MB
    unsigned short* vlt = vht + (size_t)B_ * DD * TV;                     // 2 MB

    float* out  = (float*)d_out;
    float* ctx  = out;                                     // [B][TQ][DD]
    float* attn = out + (size_t)B_ * TQ * DD;              // [B][TQ][TV]

    proj_kernel<<<dim3(TQ/8, B_, 2), 256, 0, stream>>>(query, value, W1, W2, eq, ek);
    vsplit_kernel<<<dim3(TV/64, DD/64, B_), 256, 0, stream>>>(value, vht, vlt);
    fused_kernel<<<dim3(TQ/QB, B_), 1024, 0, stream>>>(eq, ek, scale, attn);
    ctx_kernel<<<dim3((B_*TQ)/32, DD/64), 256, 0, stream>>>(attn, vht, vlt, ctx);
}

// Round 15
// 100.259 us; speedup vs baseline: 1.0585x; 1.0306x over previous
//
#include <hip/hip_runtime.h>

#define B_  2
#define TQ  1024
#define TV  1024
#define DD  512
#define UU  128

#define QB  4            // q-rows per fused block

typedef __attribute__((ext_vector_type(8))) short short8;
typedef __attribute__((ext_vector_type(4))) float f32x4;

__device__ __forceinline__ unsigned short f2bf(float x){
    unsigned int u = __float_as_uint(x);
    unsigned int r = (u + 0x7FFFu + ((u >> 16) & 1u)) >> 16;
    return (unsigned short)r;
}
__device__ __forceinline__ float bf2f(unsigned short h){
    return __uint_as_float(((unsigned int)h) << 16);
}

// ---------------- projections + exp2, block-internal k-split ----------------
// EQ = exp2(C*query@W1), EK = exp2(C*value@W2), C = 2*log2(e)
// block = 512 thr = 4 groups x 128 u; group g does 4 rows over k in [g*128, g*128+128).
// grid 1024 -> 4 blocks/CU -> 32 waves/CU.
__global__ __launch_bounds__(512, 8)
void proj_kernel(const float* __restrict__ query, const float* __restrict__ value,
                 const float* __restrict__ W1,    const float* __restrict__ W2,
                 float* __restrict__ eq, float* __restrict__ ek){
    __shared__ float red[4][4][UU];   // 8 KB
    const float TWO_LOG2E = 2.8853900817779268f;
    const int qk = blockIdx.z;
    const int b  = blockIdx.y;
    const float* X = qk ? value : query;
    const float* W = qk ? W2    : W1;
    float* out     = qk ? ek    : eq;

    const int tid = threadIdx.x;
    const int g   = tid >> 7;          // k-quarter 0..3
    const int u   = tid & 127;
    const int t0  = blockIdx.x * 4;
    const float* x  = X + ((size_t)b * TQ + t0) * DD + g * 128;
    const float* Wg = W + (size_t)g * 128 * UU + u;

    float a0 = 0.f, a1 = 0.f, a2 = 0.f, a3 = 0.f;
    #pragma unroll 2
    for (int d = 0; d < 128; d += 4){
        float w0 = Wg[(size_t)(d+0)*UU];
        float w1 = Wg[(size_t)(d+1)*UU];
        float w2 = Wg[(size_t)(d+2)*UU];
        float w3 = Wg[(size_t)(d+3)*UU];
        float4 x0 = *reinterpret_cast<const float4*>(x + 0*DD + d);
        float4 x1 = *reinterpret_cast<const float4*>(x + 1*DD + d);
        float4 x2 = *reinterpret_cast<const float4*>(x + 2*DD + d);
        float4 x3 = *reinterpret_cast<const float4*>(x + 3*DD + d);
        a0 = fmaf(x0.x,w0,a0); a0 = fmaf(x0.y,w1,a0); a0 = fmaf(x0.z,w2,a0); a0 = fmaf(x0.w,w3,a0);
        a1 = fmaf(x1.x,w0,a1); a1 = fmaf(x1.y,w1,a1); a1 = fmaf(x1.z,w2,a1); a1 = fmaf(x1.w,w3,a1);
        a2 = fmaf(x2.x,w0,a2); a2 = fmaf(x2.y,w1,a2); a2 = fmaf(x2.z,w2,a2); a2 = fmaf(x2.w,w3,a2);
        a3 = fmaf(x3.x,w0,a3); a3 = fmaf(x3.y,w1,a3); a3 = fmaf(x3.z,w2,a3); a3 = fmaf(x3.w,w3,a3);
    }
    red[g][0][u] = a0;
    red[g][1][u] = a1;
    red[g][2][u] = a2;
    red[g][3][u] = a3;
    __syncthreads();

    // tid -> output (row r = tid>>7, col u)
    {
        const int r  = tid >> 7;
        const int uu = tid & 127;
        float s = (red[0][r][uu] + red[1][r][uu]) + (red[2][r][uu] + red[3][r][uu]);
        out[((size_t)b * TQ + t0 + r) * UU + uu] = __builtin_amdgcn_exp2f(TWO_LOG2E * s);
    }
}

// ---------------- V transpose + bf16 h/l split (one-shot) ----------------
__global__ __launch_bounds__(256)
void vsplit_kernel(const float* __restrict__ value,
                   unsigned short* __restrict__ vht, unsigned short* __restrict__ vlt){
    __shared__ float t[64][65];
    const int b  = blockIdx.z;
    const int k0 = blockIdx.x * 64;
    const int d0 = blockIdx.y * 64;
    const int tid = threadIdx.x;

    #pragma unroll
    for (int i = 0; i < 4; ++i){
        int r = (tid >> 4) + 16*i;
        int c = (tid & 15) * 4;
        float4 v = *reinterpret_cast<const float4*>(value + ((size_t)b*TV + k0 + r)*DD + d0 + c);
        t[r][c+0]=v.x; t[r][c+1]=v.y; t[r][c+2]=v.z; t[r][c+3]=v.w;
    }
    __syncthreads();

    const int dr = tid >> 2;
    const int kc = (tid & 3) * 16;
    #pragma unroll
    for (int g = 0; g < 2; ++g){
        unsigned short h8[8], l8[8];
        #pragma unroll
        for (int e = 0; e < 8; ++e){
            float v = t[kc + g*8 + e][dr];
            unsigned short h = f2bf(v);
            h8[e] = h; l8[e] = f2bf(v - bf2f(h));
        }
        size_t o = ((size_t)b*DD + d0 + dr)*TV + k0 + kc + g*8;
        *reinterpret_cast<int4*>(vht + o) = *reinterpret_cast<const int4*>(h8);
        *reinterpret_cast<int4*>(vlt + o) = *reinterpret_cast<const int4*>(l8);
    }
}

// ---------------- fused scores + softmax (UNCHANGED) ----------------
__global__ __launch_bounds__(1024, 8)
void fused_kernel(const float* __restrict__ eq, const float* __restrict__ ek,
                  const float* __restrict__ scale, float* __restrict__ attn){
    __shared__ float qs[QB][UU];
    __shared__ float sc[UU];
    __shared__ float sm[QB][TV];
    __shared__ float pmax[QB][4];
    __shared__ float psum[QB][4];

    const float LOG2E = 1.4426950408889634f;
    const int b   = blockIdx.y;
    const int q0  = blockIdx.x * QB;
    const int tid = threadIdx.x;
    const int w   = tid >> 6, lane = tid & 63;

    if (tid < QB*UU)
        qs[tid >> 7][tid & 127] = eq[((size_t)b * TQ + q0 + (tid >> 7)) * UU + (tid & 127)];
    if (tid < UU)
        sc[tid] = -2.0f * scale[tid];
    __syncthreads();

    const float4* ekv = reinterpret_cast<const float4*>(ek + (size_t)b * TV * UU);
    const float4* qs4 = reinterpret_cast<const float4*>(&qs[0][0]);
    const float4* sc4 = reinterpret_cast<const float4*>(&sc[0]);

    const int kA = w*64 + lane;
    const size_t iA = (size_t)kA * 32;

    float acc[QB] = {};
    float4 kva = ekv[iA];

    for (int j = 0; j < 32; ++j){
        float4 nka;
        if (j != 31) nka = ekv[iA + j + 1];
        float4 s4 = sc4[j];
        #pragma unroll
        for (int r = 0; r < QB; ++r){
            float4 q4 = qs4[r*32 + j];
            acc[r] = fmaf(s4.x, __builtin_amdgcn_rcpf(fmaf(q4.x, kva.x, 1.0f)), acc[r]);
            acc[r] = fmaf(s4.y, __builtin_amdgcn_rcpf(fmaf(q4.y, kva.y, 1.0f)), acc[r]);
            acc[r] = fmaf(s4.z, __builtin_amdgcn_rcpf(fmaf(q4.z, kva.z, 1.0f)), acc[r]);
            acc[r] = fmaf(s4.w, __builtin_amdgcn_rcpf(fmaf(q4.w, kva.w, 1.0f)), acc[r]);
        }
        kva = nka;
    }

    #pragma unroll
    for (int r = 0; r < QB; ++r) sm[r][kA] = acc[r];
    __syncthreads();

    {
        const int r   = w & 3;
        const int seg = w >> 2;
        float s[4];
        #pragma unroll
        for (int t = 0; t < 4; ++t) s[t] = sm[r][seg*256 + t*64 + lane];

        float m = fmaxf(fmaxf(s[0], s[1]), fmaxf(s[2], s[3]));
        #pragma unroll
        for (int off = 32; off >= 1; off >>= 1) m = fmaxf(m, __shfl_xor(m, off, 64));
        if (lane == 0) pmax[r][seg] = m;
        __syncthreads();

        float M = fmaxf(fmaxf(pmax[r][0], pmax[r][1]), fmaxf(pmax[r][2], pmax[r][3]));
        float sum = 0.f;
        #pragma unroll
        for (int t = 0; t < 4; ++t){ s[t] = __builtin_amdgcn_exp2f((s[t] - M) * LOG2E); sum += s[t]; }
        #pragma unroll
        for (int off = 32; off >= 1; off >>= 1) sum += __shfl_xor(sum, off, 64);
        if (lane == 0) psum[r][seg] = sum;
        __syncthreads();

        float S = (psum[r][0] + psum[r][1]) + (psum[r][2] + psum[r][3]);
        float inv = 1.0f / S;

        float* arow = attn + ((size_t)b * TQ + q0 + r) * TV + seg*256;
        #pragma unroll
        for (int t = 0; t < 4; ++t) arow[t*64 + lane] = s[t] * inv;
    }
}

// ---------------- context = attn @ value via bf16-split MFMA (UNCHANGED) ----------------
__global__ __launch_bounds__(256, 2)
void ctx_kernel(const float* __restrict__ attn,
                const unsigned short* __restrict__ vht, const unsigned short* __restrict__ vlt,
                float* __restrict__ ctx){
    __shared__ unsigned short Ah[32*64], Al[32*64], Vh[64*64], Vl[64*64];

    const int m0   = blockIdx.x * 32;
    const int n0   = blockIdx.y * 64;
    const int b    = m0 >> 10;
    const int tid  = threadIdx.x;
    const int lane = tid & 63;
    const int w    = tid >> 6;

    const int am = tid >> 3;
    const int kq = (tid & 7) * 8;
    const int cn = tid >> 2;
    const int kv = (tid & 3) * 16;

    const float*          arow  = attn + (size_t)(m0 + am) * TV;
    const unsigned short* vhrow = vht + ((size_t)b * DD + n0 + cn) * TV;
    const unsigned short* vlrow = vlt + ((size_t)b * DD + n0 + cn) * TV;

    float ra[8];
    int4 rvh0, rvh1, rvl0, rvl1;
    #pragma unroll
    for (int i = 0; i < 2; ++i)
        *reinterpret_cast<float4*>(&ra[i*4]) = *reinterpret_cast<const float4*>(arow + kq + i*4);
    rvh0 = *reinterpret_cast<const int4*>(vhrow + kv);
    rvh1 = *reinterpret_cast<const int4*>(vhrow + kv + 8);
    rvl0 = *reinterpret_cast<const int4*>(vlrow + kv);
    rvl1 = *reinterpret_cast<const int4*>(vlrow + kv + 8);

    f32x4 acc[2];
    acc[0] = (f32x4){0.f,0.f,0.f,0.f};
    acc[1] = (f32x4){0.f,0.f,0.f,0.f};

    const int ga  = (kq >> 3) ^ (am & 7);
    const int gv0 = ((kv >> 3) + 0) ^ (cn & 7);
    const int gv1 = ((kv >> 3) + 1) ^ (cn & 7);

    for (int kt = 0; kt < TV; kt += 64){
        {
            unsigned short h8[8], l8[8];
            #pragma unroll
            for (int e = 0; e < 8; ++e){
                float a = ra[e];
                unsigned short h = f2bf(a);
                h8[e] = h; l8[e] = f2bf(a - bf2f(h));
            }
            *reinterpret_cast<int4*>(&Ah[am*64 + ga*8]) = *reinterpret_cast<const int4*>(h8);
            *reinterpret_cast<int4*>(&Al[am*64 + ga*8]) = *reinterpret_cast<const int4*>(l8);
        }
        *reinterpret_cast<int4*>(&Vh[cn*64 + gv0*8]) = rvh0;
        *reinterpret_cast<int4*>(&Vh[cn*64 + gv1*8]) = rvh1;
        *reinterpret_cast<int4*>(&Vl[cn*64 + gv0*8]) = rvl0;
        *reinterpret_cast<int4*>(&Vl[cn*64 + gv1*8]) = rvl1;

        const int ktn = (kt + 64 < TV) ? kt + 64 : 0;
        #pragma unroll
        for (int i = 0; i < 2; ++i)
            *reinterpret_cast<float4*>(&ra[i*4]) = *reinterpret_cast<const float4*>(arow + ktn + kq + i*4);
        rvh0 = *reinterpret_cast<const int4*>(vhrow + ktn + kv);
        rvh1 = *reinterpret_cast<const int4*>(vhrow + ktn + kv + 8);
        rvl0 = *reinterpret_cast<const int4*>(vlrow + ktn + kv);
        rvl1 = *reinterpret_cast<const int4*>(vlrow + ktn + kv + 8);

        __syncthreads();

        #pragma unroll
        for (int kk = 0; kk < 2; ++kk){
            const int kg = kk*4 + (lane >> 4);
            const int g  = (kg ^ (lane & 7)) * 8;
            const int r0 = (lane & 15) * 64;
            const int c0 = (w*16 + (lane & 15)) * 64;

            short8 a0h = *reinterpret_cast<const short8*>(&Ah[r0 + g]);
            short8 a1h = *reinterpret_cast<const short8*>(&Ah[r0 + 16*64 + g]);
            short8 a0l = *reinterpret_cast<const short8*>(&Al[r0 + g]);
            short8 a1l = *reinterpret_cast<const short8*>(&Al[r0 + 16*64 + g]);
            short8 bh  = *reinterpret_cast<const short8*>(&Vh[c0 + g]);
            short8 bl  = *reinterpret_cast<const short8*>(&Vl[c0 + g]);

            acc[0] = __builtin_amdgcn_mfma_f32_16x16x32_bf16(a0h, bh, acc[0], 0, 0, 0);
            acc[0] = __builtin_amdgcn_mfma_f32_16x16x32_bf16(a0l, bh, acc[0], 0, 0, 0);
            acc[0] = __builtin_amdgcn_mfma_f32_16x16x32_bf16(a0h, bl, acc[0], 0, 0, 0);

            acc[1] = __builtin_amdgcn_mfma_f32_16x16x32_bf16(a1h, bh, acc[1], 0, 0, 0);
            acc[1] = __builtin_amdgcn_mfma_f32_16x16x32_bf16(a1l, bh, acc[1], 0, 0, 0);
            acc[1] = __builtin_amdgcn_mfma_f32_16x16x32_bf16(a1h, bl, acc[1], 0, 0, 0);
        }

        __syncthreads();
    }

    #pragma unroll
    for (int fm = 0; fm < 2; ++fm){
        const int row = m0 + fm*16 + (lane >> 4) * 4;
        const int col = n0 + w*16 + (lane & 15);
        #pragma unroll
        for (int r = 0; r < 4; ++r)
            ctx[(size_t)(row + r) * DD + col] = acc[fm][r];
    }
}

extern "C" void kernel_launch(void* const* d_in, const int* in_sizes, int n_in,
                              void* d_out, int out_size, void* d_ws, size_t ws_size,
                              hipStream_t stream){
    const float* query = (const float*)d_in[0];
    const float* value = (const float*)d_in[1];
    const float* W1    = (const float*)d_in[2];
    const float* W2    = (const float*)d_in[3];
    const float* scale = (const float*)d_in[4];

    float* eq = (float*)d_ws;                              // 1 MB
    float* ek = eq + (size_t)B_ * TQ * UU;                 // 1 MB
    unsigned short* vht = (unsigned short*)(ek + (size_t)B_ * TV * UU);   // 2 MB
    unsigned short* vlt = vht + (size_t)B_ * DD * TV;                     // 2 MB

    float* out  = (float*)d_out;
    float* ctx  = out;                                     // [B][TQ][DD]
    float* attn = out + (size_t)B_ * TQ * DD;              // [B][TQ][TV]

    proj_kernel<<<dim3(TQ/4, B_, 2), 512, 0, stream>>>(query, value, W1, W2, eq, ek);
    vsplit_kernel<<<dim3(TV/64, DD/64, B_), 256, 0, stream>>>(value, vht, vlt);
    fused_kernel<<<dim3(TQ/QB, B_), 1024, 0, stream>>>(eq, ek, scale, attn);
    ctx_kernel<<<dim3((B_*TQ)/32, DD/64), 256, 0, stream>>>(attn, vht, vlt, ctx);
}

// Round 16
// 74.430 us; speedup vs baseline: 1.4259x; 1.3470x over previous
//
#include <hip/hip_runtime.h>

#define B_  2
#define TQ  1024
#define TV  1024
#define DD  512
#define UU  128

#define QB  4            // q-rows per fused block

typedef __attribute__((ext_vector_type(8))) short short8;
typedef __attribute__((ext_vector_type(4))) float f32x4;

__device__ __forceinline__ unsigned short f2bf(float x){
    unsigned int u = __float_as_uint(x);
    unsigned int r = (u + 0x7FFFu + ((u >> 16) & 1u)) >> 16;
    return (unsigned short)r;
}
__device__ __forceinline__ float bf2f(unsigned short h){
    return __uint_as_float(((unsigned int)h) << 16);
}

// ---------------- W transpose + bf16 h/l split (one-shot, tiny) ----------------
// W[k][u] fp32 -> wth/wtl [qk][u][k] bf16 planes
__global__ __launch_bounds__(256)
void wsplit_kernel(const float* __restrict__ W1, const float* __restrict__ W2,
                   unsigned short* __restrict__ wth, unsigned short* __restrict__ wtl){
    __shared__ float t[64][65];
    const int qk = blockIdx.z;
    const int k0 = blockIdx.x * 64;
    const int u0 = blockIdx.y * 64;
    const float* W = qk ? W2 : W1;
    const int tid = threadIdx.x;

    #pragma unroll
    for (int i = 0; i < 4; ++i){
        int r = (tid >> 4) + 16*i;          // k
        int c = (tid & 15) * 4;             // u
        float4 v = *reinterpret_cast<const float4*>(W + (size_t)(k0 + r)*UU + u0 + c);
        t[r][c+0]=v.x; t[r][c+1]=v.y; t[r][c+2]=v.z; t[r][c+3]=v.w;
    }
    __syncthreads();

    const int dr = tid >> 2;                // u-row 0..63
    const int kc = (tid & 3) * 16;          // k chunk
    #pragma unroll
    for (int g = 0; g < 2; ++g){
        unsigned short h8[8], l8[8];
        #pragma unroll
        for (int e = 0; e < 8; ++e){
            float v = t[kc + g*8 + e][dr];
            unsigned short h = f2bf(v);
            h8[e] = h; l8[e] = f2bf(v - bf2f(h));
        }
        size_t o = ((size_t)qk*UU + u0 + dr)*DD + k0 + kc + g*8;
        *reinterpret_cast<int4*>(wth + o) = *reinterpret_cast<const int4*>(h8);
        *reinterpret_cast<int4*>(wtl + o) = *reinterpret_cast<const int4*>(l8);
    }
}

// ---------------- projections via bf16-split MFMA + exp2 epilogue ----------------
// EQ = exp2(C*query@W1), EK = exp2(C*value@W2), C = 2*log2(e)
// X@W ~= xh@wh + xl@wh + xh@wl. Tile 16 rows x 64 cols, K-step 64, 4 waves.
__global__ __launch_bounds__(256, 4)
void projm_kernel(const float* __restrict__ query, const float* __restrict__ value,
                  const unsigned short* __restrict__ wth, const unsigned short* __restrict__ wtl,
                  float* __restrict__ eq, float* __restrict__ ek){
    __shared__ unsigned short Ah[16*64], Al[16*64], Bh[64*64], Bl[64*64];
    const float TWO_LOG2E = 2.8853900817779268f;
    const int qk  = blockIdx.z;
    const int r0g = blockIdx.x * 16;        // flattened row in [0, B_*TQ)
    const int n0  = blockIdx.y * 64;
    const float* X = qk ? value : query;
    float* out     = qk ? ek    : eq;
    const unsigned short* WH = wth + (size_t)qk * UU * DD;
    const unsigned short* WL = wtl + (size_t)qk * UU * DD;

    const int tid  = threadIdx.x;
    const int lane = tid & 63;
    const int w    = tid >> 6;

    const int ar  = tid >> 4;               // A row 0..15
    const int akq = (tid & 15) * 4;         // A k chunk (4)
    const int bc  = tid >> 2;               // B col 0..63
    const int bkc = (tid & 3) * 16;         // B k chunk (16)

    const float*          xrow  = X + (size_t)(r0g + ar) * DD;
    const unsigned short* whrow = WH + (size_t)(n0 + bc) * DD;
    const unsigned short* wlrow = WL + (size_t)(n0 + bc) * DD;

    float4 ra = *reinterpret_cast<const float4*>(xrow + akq);
    int4 rwh0 = *reinterpret_cast<const int4*>(whrow + bkc);
    int4 rwh1 = *reinterpret_cast<const int4*>(whrow + bkc + 8);
    int4 rwl0 = *reinterpret_cast<const int4*>(wlrow + bkc);
    int4 rwl1 = *reinterpret_cast<const int4*>(wlrow + bkc + 8);

    f32x4 acc = (f32x4){0.f,0.f,0.f,0.f};

    const int ga  = (akq >> 3) ^ (ar & 7);
    const int ao  = akq & 7;
    const int gb0 = ((bkc >> 3) + 0) ^ (bc & 7);
    const int gb1 = ((bkc >> 3) + 1) ^ (bc & 7);

    for (int kt = 0; kt < DD; kt += 64){
        {
            unsigned short h4[4], l4[4];
            #pragma unroll
            for (int e = 0; e < 4; ++e){
                float a = (e==0)?ra.x:(e==1)?ra.y:(e==2)?ra.z:ra.w;
                unsigned short h = f2bf(a);
                h4[e] = h; l4[e] = f2bf(a - bf2f(h));
            }
            *reinterpret_cast<int2*>(&Ah[ar*64 + ga*8 + ao]) = *reinterpret_cast<const int2*>(h4);
            *reinterpret_cast<int2*>(&Al[ar*64 + ga*8 + ao]) = *reinterpret_cast<const int2*>(l4);
        }
        *reinterpret_cast<int4*>(&Bh[bc*64 + gb0*8]) = rwh0;
        *reinterpret_cast<int4*>(&Bh[bc*64 + gb1*8]) = rwh1;
        *reinterpret_cast<int4*>(&Bl[bc*64 + gb0*8]) = rwl0;
        *reinterpret_cast<int4*>(&Bl[bc*64 + gb1*8]) = rwl1;

        const int ktn = (kt + 64 < DD) ? kt + 64 : 0;
        ra   = *reinterpret_cast<const float4*>(xrow + ktn + akq);
        rwh0 = *reinterpret_cast<const int4*>(whrow + ktn + bkc);
        rwh1 = *reinterpret_cast<const int4*>(whrow + ktn + bkc + 8);
        rwl0 = *reinterpret_cast<const int4*>(wlrow + ktn + bkc);
        rwl1 = *reinterpret_cast<const int4*>(wlrow + ktn + bkc + 8);

        __syncthreads();

        #pragma unroll
        for (int kk = 0; kk < 2; ++kk){
            const int kg = kk*4 + (lane >> 4);
            const int g  = (kg ^ (lane & 7)) * 8;
            const int r0 = (lane & 15) * 64;
            const int c0 = (w*16 + (lane & 15)) * 64;

            short8 ah = *reinterpret_cast<const short8*>(&Ah[r0 + g]);
            short8 al = *reinterpret_cast<const short8*>(&Al[r0 + g]);
            short8 bh = *reinterpret_cast<const short8*>(&Bh[c0 + g]);
            short8 bl = *reinterpret_cast<const short8*>(&Bl[c0 + g]);

            acc = __builtin_amdgcn_mfma_f32_16x16x32_bf16(ah, bh, acc, 0, 0, 0);
            acc = __builtin_amdgcn_mfma_f32_16x16x32_bf16(al, bh, acc, 0, 0, 0);
            acc = __builtin_amdgcn_mfma_f32_16x16x32_bf16(ah, bl, acc, 0, 0, 0);
        }

        __syncthreads();
    }

    const int orow = r0g + (lane >> 4) * 4;
    const int ocol = n0 + w*16 + (lane & 15);
    #pragma unroll
    for (int r = 0; r < 4; ++r)
        out[(size_t)(orow + r) * UU + ocol] = __builtin_amdgcn_exp2f(TWO_LOG2E * acc[r]);
}

// ---------------- V transpose + bf16 h/l split (one-shot) ----------------
__global__ __launch_bounds__(256)
void vsplit_kernel(const float* __restrict__ value,
                   unsigned short* __restrict__ vht, unsigned short* __restrict__ vlt){
    __shared__ float t[64][65];
    const int b  = blockIdx.z;
    const int k0 = blockIdx.x * 64;
    const int d0 = blockIdx.y * 64;
    const int tid = threadIdx.x;

    #pragma unroll
    for (int i = 0; i < 4; ++i){
        int r = (tid >> 4) + 16*i;
        int c = (tid & 15) * 4;
        float4 v = *reinterpret_cast<const float4*>(value + ((size_t)b*TV + k0 + r)*DD + d0 + c);
        t[r][c+0]=v.x; t[r][c+1]=v.y; t[r][c+2]=v.z; t[r][c+3]=v.w;
    }
    __syncthreads();

    const int dr = tid >> 2;
    const int kc = (tid & 3) * 16;
    #pragma unroll
    for (int g = 0; g < 2; ++g){
        unsigned short h8[8], l8[8];
        #pragma unroll
        for (int e = 0; e < 8; ++e){
            float v = t[kc + g*8 + e][dr];
            unsigned short h = f2bf(v);
            h8[e] = h; l8[e] = f2bf(v - bf2f(h));
        }
        size_t o = ((size_t)b*DD + d0 + dr)*TV + k0 + kc + g*8;
        *reinterpret_cast<int4*>(vht + o) = *reinterpret_cast<const int4*>(h8);
        *reinterpret_cast<int4*>(vlt + o) = *reinterpret_cast<const int4*>(l8);
    }
}

// ---------------- fused scores + softmax (UNCHANGED) ----------------
__global__ __launch_bounds__(1024, 8)
void fused_kernel(const float* __restrict__ eq, const float* __restrict__ ek,
                  const float* __restrict__ scale, float* __restrict__ attn){
    __shared__ float qs[QB][UU];
    __shared__ float sc[UU];
    __shared__ float sm[QB][TV];
    __shared__ float pmax[QB][4];
    __shared__ float psum[QB][4];

    const float LOG2E = 1.4426950408889634f;
    const int b   = blockIdx.y;
    const int q0  = blockIdx.x * QB;
    const int tid = threadIdx.x;
    const int w   = tid >> 6, lane = tid & 63;

    if (tid < QB*UU)
        qs[tid >> 7][tid & 127] = eq[((size_t)b * TQ + q0 + (tid >> 7)) * UU + (tid & 127)];
    if (tid < UU)
        sc[tid] = -2.0f * scale[tid];
    __syncthreads();

    const float4* ekv = reinterpret_cast<const float4*>(ek + (size_t)b * TV * UU);
    const float4* qs4 = reinterpret_cast<const float4*>(&qs[0][0]);
    const float4* sc4 = reinterpret_cast<const float4*>(&sc[0]);

    const int kA = w*64 + lane;
    const size_t iA = (size_t)kA * 32;

    float acc[QB] = {};
    float4 kva = ekv[iA];

    for (int j = 0; j < 32; ++j){
        float4 nka;
        if (j != 31) nka = ekv[iA + j + 1];
        float4 s4 = sc4[j];
        #pragma unroll
        for (int r = 0; r < QB; ++r){
            float4 q4 = qs4[r*32 + j];
            acc[r] = fmaf(s4.x, __builtin_amdgcn_rcpf(fmaf(q4.x, kva.x, 1.0f)), acc[r]);
            acc[r] = fmaf(s4.y, __builtin_amdgcn_rcpf(fmaf(q4.y, kva.y, 1.0f)), acc[r]);
            acc[r] = fmaf(s4.z, __builtin_amdgcn_rcpf(fmaf(q4.z, kva.z, 1.0f)), acc[r]);
            acc[r] = fmaf(s4.w, __builtin_amdgcn_rcpf(fmaf(q4.w, kva.w, 1.0f)), acc[r]);
        }
        kva = nka;
    }

    #pragma unroll
    for (int r = 0; r < QB; ++r) sm[r][kA] = acc[r];
    __syncthreads();

    {
        const int r   = w & 3;
        const int seg = w >> 2;
        float s[4];
        #pragma unroll
        for (int t = 0; t < 4; ++t) s[t] = sm[r][seg*256 + t*64 + lane];

        float m = fmaxf(fmaxf(s[0], s[1]), fmaxf(s[2], s[3]));
        #pragma unroll
        for (int off = 32; off >= 1; off >>= 1) m = fmaxf(m, __shfl_xor(m, off, 64));
        if (lane == 0) pmax[r][seg] = m;
        __syncthreads();

        float M = fmaxf(fmaxf(pmax[r][0], pmax[r][1]), fmaxf(pmax[r][2], pmax[r][3]));
        float sum = 0.f;
        #pragma unroll
        for (int t = 0; t < 4; ++t){ s[t] = __builtin_amdgcn_exp2f((s[t] - M) * LOG2E); sum += s[t]; }
        #pragma unroll
        for (int off = 32; off >= 1; off >>= 1) sum += __shfl_xor(sum, off, 64);
        if (lane == 0) psum[r][seg] = sum;
        __syncthreads();

        float S = (psum[r][0] + psum[r][1]) + (psum[r][2] + psum[r][3]);
        float inv = 1.0f / S;

        float* arow = attn + ((size_t)b * TQ + q0 + r) * TV + seg*256;
        #pragma unroll
        for (int t = 0; t < 4; ++t) arow[t*64 + lane] = s[t] * inv;
    }
}

// ---------------- context = attn @ value via bf16-split MFMA (UNCHANGED) ----------------
__global__ __launch_bounds__(256, 2)
void ctx_kernel(const float* __restrict__ attn,
                const unsigned short* __restrict__ vht, const unsigned short* __restrict__ vlt,
                float* __restrict__ ctx){
    __shared__ unsigned short Ah[32*64], Al[32*64], Vh[64*64], Vl[64*64];

    const int m0   = blockIdx.x * 32;
    const int n0   = blockIdx.y * 64;
    const int b    = m0 >> 10;
    const int tid  = threadIdx.x;
    const int lane = tid & 63;
    const int w    = tid >> 6;

    const int am = tid >> 3;
    const int kq = (tid & 7) * 8;
    const int cn = tid >> 2;
    const int kv = (tid & 3) * 16;

    const float*          arow  = attn + (size_t)(m0 + am) * TV;
    const unsigned short* vhrow = vht + ((size_t)b * DD + n0 + cn) * TV;
    const unsigned short* vlrow = vlt + ((size_t)b * DD + n0 + cn) * TV;

    float ra[8];
    int4 rvh0, rvh1, rvl0, rvl1;
    #pragma unroll
    for (int i = 0; i < 2; ++i)
        *reinterpret_cast<float4*>(&ra[i*4]) = *reinterpret_cast<const float4*>(arow + kq + i*4);
    rvh0 = *reinterpret_cast<const int4*>(vhrow + kv);
    rvh1 = *reinterpret_cast<const int4*>(vhrow + kv + 8);
    rvl0 = *reinterpret_cast<const int4*>(vlrow + kv);
    rvl1 = *reinterpret_cast<const int4*>(vlrow + kv + 8);

    f32x4 acc[2];
    acc[0] = (f32x4){0.f,0.f,0.f,0.f};
    acc[1] = (f32x4){0.f,0.f,0.f,0.f};

    const int ga  = (kq >> 3) ^ (am & 7);
    const int gv0 = ((kv >> 3) + 0) ^ (cn & 7);
    const int gv1 = ((kv >> 3) + 1) ^ (cn & 7);

    for (int kt = 0; kt < TV; kt += 64){
        {
            unsigned short h8[8], l8[8];
            #pragma unroll
            for (int e = 0; e < 8; ++e){
                float a = ra[e];
                unsigned short h = f2bf(a);
                h8[e] = h; l8[e] = f2bf(a - bf2f(h));
            }
            *reinterpret_cast<int4*>(&Ah[am*64 + ga*8]) = *reinterpret_cast<const int4*>(h8);
            *reinterpret_cast<int4*>(&Al[am*64 + ga*8]) = *reinterpret_cast<const int4*>(l8);
        }
        *reinterpret_cast<int4*>(&Vh[cn*64 + gv0*8]) = rvh0;
        *reinterpret_cast<int4*>(&Vh[cn*64 + gv1*8]) = rvh1;
        *reinterpret_cast<int4*>(&Vl[cn*64 + gv0*8]) = rvl0;
        *reinterpret_cast<int4*>(&Vl[cn*64 + gv1*8]) = rvl1;

        const int ktn = (kt + 64 < TV) ? kt + 64 : 0;
        #pragma unroll
        for (int i = 0; i < 2; ++i)
            *reinterpret_cast<float4*>(&ra[i*4]) = *reinterpret_cast<const float4*>(arow + ktn + kq + i*4);
        rvh0 = *reinterpret_cast<const int4*>(vhrow + ktn + kv);
        rvh1 = *reinterpret_cast<const int4*>(vhrow + ktn + kv + 8);
        rvl0 = *reinterpret_cast<const int4*>(vlrow + ktn + kv);
        rvl1 = *reinterpret_cast<const int4*>(vlrow + ktn + kv + 8);

        __syncthreads();

        #pragma unroll
        for (int kk = 0; kk < 2; ++kk){
            const int kg = kk*4 + (lane >> 4);
            const int g  = (kg ^ (lane & 7)) * 8;
            const int r0 = (lane & 15) * 64;
            const int c0 = (w*16 + (lane & 15)) * 64;

            short8 a0h = *reinterpret_cast<const short8*>(&Ah[r0 + g]);
            short8 a1h = *reinterpret_cast<const short8*>(&Ah[r0 + 16*64 + g]);
            short8 a0l = *reinterpret_cast<const short8*>(&Al[r0 + g]);
            short8 a1l = *reinterpret_cast<const short8*>(&Al[r0 + 16*64 + g]);
            short8 bh  = *reinterpret_cast<const short8*>(&Vh[c0 + g]);
            short8 bl  = *reinterpret_cast<const short8*>(&Vl[c0 + g]);

            acc[0] = __builtin_amdgcn_mfma_f32_16x16x32_bf16(a0h, bh, acc[0], 0, 0, 0);
            acc[0] = __builtin_amdgcn_mfma_f32_16x16x32_bf16(a0l, bh, acc[0], 0, 0, 0);
            acc[0] = __builtin_amdgcn_mfma_f32_16x16x32_bf16(a0h, bl, acc[0], 0, 0, 0);

            acc[1] = __builtin_amdgcn_mfma_f32_16x16x32_bf16(a1h, bh, acc[1], 0, 0, 0);
            acc[1] = __builtin_amdgcn_mfma_f32_16x16x32_bf16(a1l, bh, acc[1], 0, 0, 0);
            acc[1] = __builtin_amdgcn_mfma_f32_16x16x32_bf16(a1h, bl, acc[1], 0, 0, 0);
        }

        __syncthreads();
    }

    #pragma unroll
    for (int fm = 0; fm < 2; ++fm){
        const int row = m0 + fm*16 + (lane >> 4) * 4;
        const int col = n0 + w*16 + (lane & 15);
        #pragma unroll
        for (int r = 0; r < 4; ++r)
            ctx[(size_t)(row + r) * DD + col] = acc[fm][r];
    }
}

extern "C" void kernel_launch(void* const* d_in, const int* in_sizes, int n_in,
                              void* d_out, int out_size, void* d_ws, size_t ws_size,
                              hipStream_t stream){
    const float* query = (const float*)d_in[0];
    const float* value = (const float*)d_in[1];
    const float* W1    = (const float*)d_in[2];
    const float* W2    = (const float*)d_in[3];
    const float* scale = (const float*)d_in[4];

    float* eq = (float*)d_ws;                              // 1 MB
    float* ek = eq + (size_t)B_ * TQ * UU;                 // 1 MB
    unsigned short* vht = (unsigned short*)(ek + (size_t)B_ * TV * UU);   // 2 MB
    unsigned short* vlt = vht + (size_t)B_ * DD * TV;                     // 2 MB
    unsigned short* wth = vlt + (size_t)B_ * DD * TV;                     // 256 KB
    unsigned short* wtl = wth + (size_t)2 * UU * DD;                      // 256 KB

    float* out  = (float*)d_out;
    float* ctx  = out;                                     // [B][TQ][DD]
    float* attn = out + (size_t)B_ * TQ * DD;              // [B][TQ][TV]

    wsplit_kernel<<<dim3(DD/64, UU/64, 2), 256, 0, stream>>>(W1, W2, wth, wtl);
    vsplit_kernel<<<dim3(TV/64, DD/64, B_), 256, 0, stream>>>(value, vht, vlt);
    projm_kernel<<<dim3((B_*TQ)/16, UU/64, 2), 256, 0, stream>>>(query, value, wth, wtl, eq, ek);
    fused_kernel<<<dim3(TQ/QB, B_), 1024, 0, stream>>>(eq, ek, scale, attn);
    ctx_kernel<<<dim3((B_*TQ)/32, DD/64), 256, 0, stream>>>(attn, vht, vlt, ctx);
}

// Round 17
// 69.094 us; speedup vs baseline: 1.5360x; 1.0772x over previous
//
#include <hip/hip_runtime.h>

#define B_  2
#define TQ  1024
#define TV  1024
#define DD  512
#define UU  128

#define QB  4            // q-rows per fused block

typedef __attribute__((ext_vector_type(8))) short short8;
typedef __attribute__((ext_vector_type(4))) float f32x4;

__device__ __forceinline__ unsigned short f2bf(float x){
    unsigned int u = __float_as_uint(x);
    unsigned int r = (u + 0x7FFFu + ((u >> 16) & 1u)) >> 16;
    return (unsigned short)r;
}
__device__ __forceinline__ float bf2f(unsigned short h){
    return __uint_as_float(((unsigned int)h) << 16);
}

// ---------------- merged one-shot transposes: V and W -> bf16 h/l planes ----------------
// blocks [0,256): value [b][k][d] -> vht/vlt [b][d][k]
// blocks [256,288): W[k][u] -> wth/wtl [qk][u][k]
__global__ __launch_bounds__(256)
void split_kernel(const float* __restrict__ value,
                  const float* __restrict__ W1, const float* __restrict__ W2,
                  unsigned short* __restrict__ vht, unsigned short* __restrict__ vlt,
                  unsigned short* __restrict__ wth, unsigned short* __restrict__ wtl){
    __shared__ float t[64][65];
    const int bid = blockIdx.x;
    const int tid = threadIdx.x;

    const float* src;
    unsigned short *dh, *dl;
    int k0, c0;          // source row block (k), source col block
    size_t orow_base;    // dest: (row=c, col=k)
    int src_ld, dst_ld;

    if (bid < 256){
        const int b   = bid >> 7;
        const int rem = bid & 127;
        k0 = (rem >> 3) * 64;
        c0 = (rem & 7) * 64;
        src = value + (size_t)b * TV * DD;
        src_ld = DD; dst_ld = TV;
        orow_base = (size_t)b * DD;
        dh = vht; dl = vlt;
    } else {
        const int wb  = bid - 256;
        const int qk  = wb >> 4;
        const int rem = wb & 15;
        k0 = (rem >> 1) * 64;
        c0 = (rem & 1) * 64;
        src = (qk ? W2 : W1);
        src_ld = UU; dst_ld = DD;
        orow_base = (size_t)qk * UU;
        dh = wth; dl = wtl;
    }

    #pragma unroll
    for (int i = 0; i < 4; ++i){
        int r = (tid >> 4) + 16*i;
        int c = (tid & 15) * 4;
        float4 v = *reinterpret_cast<const float4*>(src + (size_t)(k0 + r)*src_ld + c0 + c);
        t[r][c+0]=v.x; t[r][c+1]=v.y; t[r][c+2]=v.z; t[r][c+3]=v.w;
    }
    __syncthreads();

    const int dr = tid >> 2;
    const int kc = (tid & 3) * 16;
    #pragma unroll
    for (int g = 0; g < 2; ++g){
        unsigned short h8[8], l8[8];
        #pragma unroll
        for (int e = 0; e < 8; ++e){
            float v = t[kc + g*8 + e][dr];
            unsigned short h = f2bf(v);
            h8[e] = h; l8[e] = f2bf(v - bf2f(h));
        }
        size_t o = (orow_base + c0 + dr)*(size_t)dst_ld + k0 + kc + g*8;
        *reinterpret_cast<int4*>(dh + o) = *reinterpret_cast<const int4*>(h8);
        *reinterpret_cast<int4*>(dl + o) = *reinterpret_cast<const int4*>(l8);
    }
}

// ---------------- projections via bf16-split MFMA + exp2 epilogue (UNCHANGED) ----------------
__global__ __launch_bounds__(256, 4)
void projm_kernel(const float* __restrict__ query, const float* __restrict__ value,
                  const unsigned short* __restrict__ wth, const unsigned short* __restrict__ wtl,
                  float* __restrict__ eq, float* __restrict__ ek){
    __shared__ unsigned short Ah[16*64], Al[16*64], Bh[64*64], Bl[64*64];
    const float TWO_LOG2E = 2.8853900817779268f;
    const int qk  = blockIdx.z;
    const int r0g = blockIdx.x * 16;
    const int n0  = blockIdx.y * 64;
    const float* X = qk ? value : query;
    float* out     = qk ? ek    : eq;
    const unsigned short* WH = wth + (size_t)qk * UU * DD;
    const unsigned short* WL = wtl + (size_t)qk * UU * DD;

    const int tid  = threadIdx.x;
    const int lane = tid & 63;
    const int w    = tid >> 6;

    const int ar  = tid >> 4;
    const int akq = (tid & 15) * 4;
    const int bc  = tid >> 2;
    const int bkc = (tid & 3) * 16;

    const float*          xrow  = X + (size_t)(r0g + ar) * DD;
    const unsigned short* whrow = WH + (size_t)(n0 + bc) * DD;
    const unsigned short* wlrow = WL + (size_t)(n0 + bc) * DD;

    float4 ra = *reinterpret_cast<const float4*>(xrow + akq);
    int4 rwh0 = *reinterpret_cast<const int4*>(whrow + bkc);
    int4 rwh1 = *reinterpret_cast<const int4*>(whrow + bkc + 8);
    int4 rwl0 = *reinterpret_cast<const int4*>(wlrow + bkc);
    int4 rwl1 = *reinterpret_cast<const int4*>(wlrow + bkc + 8);

    f32x4 acc = (f32x4){0.f,0.f,0.f,0.f};

    const int ga  = (akq >> 3) ^ (ar & 7);
    const int ao  = akq & 7;
    const int gb0 = ((bkc >> 3) + 0) ^ (bc & 7);
    const int gb1 = ((bkc >> 3) + 1) ^ (bc & 7);

    for (int kt = 0; kt < DD; kt += 64){
        {
            unsigned short h4[4], l4[4];
            #pragma unroll
            for (int e = 0; e < 4; ++e){
                float a = (e==0)?ra.x:(e==1)?ra.y:(e==2)?ra.z:ra.w;
                unsigned short h = f2bf(a);
                h4[e] = h; l4[e] = f2bf(a - bf2f(h));
            }
            *reinterpret_cast<int2*>(&Ah[ar*64 + ga*8 + ao]) = *reinterpret_cast<const int2*>(h4);
            *reinterpret_cast<int2*>(&Al[ar*64 + ga*8 + ao]) = *reinterpret_cast<const int2*>(l4);
        }
        *reinterpret_cast<int4*>(&Bh[bc*64 + gb0*8]) = rwh0;
        *reinterpret_cast<int4*>(&Bh[bc*64 + gb1*8]) = rwh1;
        *reinterpret_cast<int4*>(&Bl[bc*64 + gb0*8]) = rwl0;
        *reinterpret_cast<int4*>(&Bl[bc*64 + gb1*8]) = rwl1;

        const int ktn = (kt + 64 < DD) ? kt + 64 : 0;
        ra   = *reinterpret_cast<const float4*>(xrow + ktn + akq);
        rwh0 = *reinterpret_cast<const int4*>(whrow + ktn + bkc);
        rwh1 = *reinterpret_cast<const int4*>(whrow + ktn + bkc + 8);
        rwl0 = *reinterpret_cast<const int4*>(wlrow + ktn + bkc);
        rwl1 = *reinterpret_cast<const int4*>(wlrow + ktn + bkc + 8);

        __syncthreads();

        #pragma unroll
        for (int kk = 0; kk < 2; ++kk){
            const int kg = kk*4 + (lane >> 4);
            const int g  = (kg ^ (lane & 7)) * 8;
            const int r0 = (lane & 15) * 64;
            const int c0 = (w*16 + (lane & 15)) * 64;

            short8 ah = *reinterpret_cast<const short8*>(&Ah[r0 + g]);
            short8 al = *reinterpret_cast<const short8*>(&Al[r0 + g]);
            short8 bh = *reinterpret_cast<const short8*>(&Bh[c0 + g]);
            short8 bl = *reinterpret_cast<const short8*>(&Bl[c0 + g]);

            acc = __builtin_amdgcn_mfma_f32_16x16x32_bf16(ah, bh, acc, 0, 0, 0);
            acc = __builtin_amdgcn_mfma_f32_16x16x32_bf16(al, bh, acc, 0, 0, 0);
            acc = __builtin_amdgcn_mfma_f32_16x16x32_bf16(ah, bl, acc, 0, 0, 0);
        }

        __syncthreads();
    }

    const int orow = r0g + (lane >> 4) * 4;
    const int ocol = n0 + w*16 + (lane & 15);
    #pragma unroll
    for (int r = 0; r < 4; ++r)
        out[(size_t)(orow + r) * UU + ocol] = __builtin_amdgcn_exp2f(TWO_LOG2E * acc[r]);
}

// ---------------- fused scores + softmax, q/scale via scalar (uniform) loads ----------------
// score[q,k] = -2 * sum_u scale[u] * rcp(1 + EQ[q,u]*EK[k,u])  (+const, cancels in softmax)
// q4/s4 are wave-uniform -> s_load (SMEM pipe); LDS-free inner loop. No-max softmax.
__global__ __launch_bounds__(1024, 8)
void fused_kernel(const float* __restrict__ eq, const float* __restrict__ ek,
                  const float* __restrict__ scale, float* __restrict__ attn){
    __shared__ float sm[QB][TV];
    __shared__ float psum[QB][4];

    const float LOG2E = 1.4426950408889634f;
    const int b   = blockIdx.y;
    const int q0  = blockIdx.x * QB;
    const int tid = threadIdx.x;
    const int w   = tid >> 6, lane = tid & 63;

    const float* qr0 = eq + ((size_t)b * TQ + q0 + 0) * UU;
    const float* qr1 = eq + ((size_t)b * TQ + q0 + 1) * UU;
    const float* qr2 = eq + ((size_t)b * TQ + q0 + 2) * UU;
    const float* qr3 = eq + ((size_t)b * TQ + q0 + 3) * UU;

    const float4* ekv = reinterpret_cast<const float4*>(ek + (size_t)b * TV * UU);

    const int kA = w*64 + lane;
    const size_t iA = (size_t)kA * 32;

    float acc[QB] = {};
    float4 kva = ekv[iA];

    for (int j = 0; j < 32; ++j){
        float4 nka;
        if (j != 31) nka = ekv[iA + j + 1];
        float4 s4 = *reinterpret_cast<const float4*>(scale + j*4);
        float4 q4;
        q4 = *reinterpret_cast<const float4*>(qr0 + j*4);
        acc[0] = fmaf(s4.x, __builtin_amdgcn_rcpf(fmaf(q4.x, kva.x, 1.0f)), acc[0]);
        acc[0] = fmaf(s4.y, __builtin_amdgcn_rcpf(fmaf(q4.y, kva.y, 1.0f)), acc[0]);
        acc[0] = fmaf(s4.z, __builtin_amdgcn_rcpf(fmaf(q4.z, kva.z, 1.0f)), acc[0]);
        acc[0] = fmaf(s4.w, __builtin_amdgcn_rcpf(fmaf(q4.w, kva.w, 1.0f)), acc[0]);
        q4 = *reinterpret_cast<const float4*>(qr1 + j*4);
        acc[1] = fmaf(s4.x, __builtin_amdgcn_rcpf(fmaf(q4.x, kva.x, 1.0f)), acc[1]);
        acc[1] = fmaf(s4.y, __builtin_amdgcn_rcpf(fmaf(q4.y, kva.y, 1.0f)), acc[1]);
        acc[1] = fmaf(s4.z, __builtin_amdgcn_rcpf(fmaf(q4.z, kva.z, 1.0f)), acc[1]);
        acc[1] = fmaf(s4.w, __builtin_amdgcn_rcpf(fmaf(q4.w, kva.w, 1.0f)), acc[1]);
        q4 = *reinterpret_cast<const float4*>(qr2 + j*4);
        acc[2] = fmaf(s4.x, __builtin_amdgcn_rcpf(fmaf(q4.x, kva.x, 1.0f)), acc[2]);
        acc[2] = fmaf(s4.y, __builtin_amdgcn_rcpf(fmaf(q4.y, kva.y, 1.0f)), acc[2]);
        acc[2] = fmaf(s4.z, __builtin_amdgcn_rcpf(fmaf(q4.z, kva.z, 1.0f)), acc[2]);
        acc[2] = fmaf(s4.w, __builtin_amdgcn_rcpf(fmaf(q4.w, kva.w, 1.0f)), acc[2]);
        q4 = *reinterpret_cast<const float4*>(qr3 + j*4);
        acc[3] = fmaf(s4.x, __builtin_amdgcn_rcpf(fmaf(q4.x, kva.x, 1.0f)), acc[3]);
        acc[3] = fmaf(s4.y, __builtin_amdgcn_rcpf(fmaf(q4.y, kva.y, 1.0f)), acc[3]);
        acc[3] = fmaf(s4.z, __builtin_amdgcn_rcpf(fmaf(q4.z, kva.z, 1.0f)), acc[3]);
        acc[3] = fmaf(s4.w, __builtin_amdgcn_rcpf(fmaf(q4.w, kva.w, 1.0f)), acc[3]);
        kva = nka;
    }

    #pragma unroll
    for (int r = 0; r < QB; ++r) sm[r][kA] = -2.0f * acc[r];
    __syncthreads();

    // no-max softmax: wave w -> row r = w&3, segment seg = w>>2 (256 k)
    {
        const int r   = w & 3;
        const int seg = w >> 2;
        float s[4];
        #pragma unroll
        for (int t = 0; t < 4; ++t) s[t] = sm[r][seg*256 + t*64 + lane];

        float sum = 0.f;
        #pragma unroll
        for (int t = 0; t < 4; ++t){ s[t] = __builtin_amdgcn_exp2f(s[t] * LOG2E); sum += s[t]; }
        #pragma unroll
        for (int off = 32; off >= 1; off >>= 1) sum += __shfl_xor(sum, off, 64);
        if (lane == 0) psum[r][seg] = sum;
        __syncthreads();

        float S = (psum[r][0] + psum[r][1]) + (psum[r][2] + psum[r][3]);
        float inv = 1.0f / S;

        float* arow = attn + ((size_t)b * TQ + q0 + r) * TV + seg*256;
        #pragma unroll
        for (int t = 0; t < 4; ++t) arow[t*64 + lane] = s[t] * inv;
    }
}

// ---------------- context = attn @ value via bf16-split MFMA (UNCHANGED) ----------------
__global__ __launch_bounds__(256, 2)
void ctx_kernel(const float* __restrict__ attn,
                const unsigned short* __restrict__ vht, const unsigned short* __restrict__ vlt,
                float* __restrict__ ctx){
    __shared__ unsigned short Ah[32*64], Al[32*64], Vh[64*64], Vl[64*64];

    const int m0   = blockIdx.x * 32;
    const int n0   = blockIdx.y * 64;
    const int b    = m0 >> 10;
    const int tid  = threadIdx.x;
    const int lane = tid & 63;
    const int w    = tid >> 6;

    const int am = tid >> 3;
    const int kq = (tid & 7) * 8;
    const int cn = tid >> 2;
    const int kv = (tid & 3) * 16;

    const float*          arow  = attn + (size_t)(m0 + am) * TV;
    const unsigned short* vhrow = vht + ((size_t)b * DD + n0 + cn) * TV;
    const unsigned short* vlrow = vlt + ((size_t)b * DD + n0 + cn) * TV;

    float ra[8];
    int4 rvh0, rvh1, rvl0, rvl1;
    #pragma unroll
    for (int i = 0; i < 2; ++i)
        *reinterpret_cast<float4*>(&ra[i*4]) = *reinterpret_cast<const float4*>(arow + kq + i*4);
    rvh0 = *reinterpret_cast<const int4*>(vhrow + kv);
    rvh1 = *reinterpret_cast<const int4*>(vhrow + kv + 8);
    rvl0 = *reinterpret_cast<const int4*>(vlrow + kv);
    rvl1 = *reinterpret_cast<const int4*>(vlrow + kv + 8);

    f32x4 acc[2];
    acc[0] = (f32x4){0.f,0.f,0.f,0.f};
    acc[1] = (f32x4){0.f,0.f,0.f,0.f};

    const int ga  = (kq >> 3) ^ (am & 7);
    const int gv0 = ((kv >> 3) + 0) ^ (cn & 7);
    const int gv1 = ((kv >> 3) + 1) ^ (cn & 7);

    for (int kt = 0; kt < TV; kt += 64){
        {
            unsigned short h8[8], l8[8];
            #pragma unroll
            for (int e = 0; e < 8; ++e){
                float a = ra[e];
                unsigned short h = f2bf(a);
                h8[e] = h; l8[e] = f2bf(a - bf2f(h));
            }
            *reinterpret_cast<int4*>(&Ah[am*64 + ga*8]) = *reinterpret_cast<const int4*>(h8);
            *reinterpret_cast<int4*>(&Al[am*64 + ga*8]) = *reinterpret_cast<const int4*>(l8);
        }
        *reinterpret_cast<int4*>(&Vh[cn*64 + gv0*8]) = rvh0;
        *reinterpret_cast<int4*>(&Vh[cn*64 + gv1*8]) = rvh1;
        *reinterpret_cast<int4*>(&Vl[cn*64 + gv0*8]) = rvl0;
        *reinterpret_cast<int4*>(&Vl[cn*64 + gv1*8]) = rvl1;

        const int ktn = (kt + 64 < TV) ? kt + 64 : 0;
        #pragma unroll
        for (int i = 0; i < 2; ++i)
            *reinterpret_cast<float4*>(&ra[i*4]) = *reinterpret_cast<const float4*>(arow + ktn + kq + i*4);
        rvh0 = *reinterpret_cast<const int4*>(vhrow + ktn + kv);
        rvh1 = *reinterpret_cast<const int4*>(vhrow + ktn + kv + 8);
        rvl0 = *reinterpret_cast<const int4*>(vlrow + ktn + kv);
        rvl1 = *reinterpret_cast<const int4*>(vlrow + ktn + kv + 8);

        __syncthreads();

        #pragma unroll
        for (int kk = 0; kk < 2; ++kk){
            const int kg = kk*4 + (lane >> 4);
            const int g  = (kg ^ (lane & 7)) * 8;
            const int r0 = (lane & 15) * 64;
            const int c0 = (w*16 + (lane & 15)) * 64;

            short8 a0h = *reinterpret_cast<const short8*>(&Ah[r0 + g]);
            short8 a1h = *reinterpret_cast<const short8*>(&Ah[r0 + 16*64 + g]);
            short8 a0l = *reinterpret_cast<const short8*>(&Al[r0 + g]);
            short8 a1l = *reinterpret_cast<const short8*>(&Al[r0 + 16*64 + g]);
            short8 bh  = *reinterpret_cast<const short8*>(&Vh[c0 + g]);
            short8 bl  = *reinterpret_cast<const short8*>(&Vl[c0 + g]);

            acc[0] = __builtin_amdgcn_mfma_f32_16x16x32_bf16(a0h, bh, acc[0], 0, 0, 0);
            acc[0] = __builtin_amdgcn_mfma_f32_16x16x32_bf16(a0l, bh, acc[0], 0, 0, 0);
            acc[0] = __builtin_amdgcn_mfma_f32_16x16x32_bf16(a0h, bl, acc[0], 0, 0, 0);

            acc[1] = __builtin_amdgcn_mfma_f32_16x16x32_bf16(a1h, bh, acc[1], 0, 0, 0);
            acc[1] = __builtin_amdgcn_mfma_f32_16x16x32_bf16(a1l, bh, acc[1], 0, 0, 0);
            acc[1] = __builtin_amdgcn_mfma_f32_16x16x32_bf16(a1h, bl, acc[1], 0, 0, 0);
        }

        __syncthreads();
    }

    #pragma unroll
    for (int fm = 0; fm < 2; ++fm){
        const int row = m0 + fm*16 + (lane >> 4) * 4;
        const int col = n0 + w*16 + (lane & 15);
        #pragma unroll
        for (int r = 0; r < 4; ++r)
            ctx[(size_t)(row + r) * DD + col] = acc[fm][r];
    }
}

extern "C" void kernel_launch(void* const* d_in, const int* in_sizes, int n_in,
                              void* d_out, int out_size, void* d_ws, size_t ws_size,
                              hipStream_t stream){
    const float* query = (const float*)d_in[0];
    const float* value = (const float*)d_in[1];
    const float* W1    = (const float*)d_in[2];
    const float* W2    = (const float*)d_in[3];
    const float* scale = (const float*)d_in[4];

    float* eq = (float*)d_ws;                              // 1 MB
    float* ek = eq + (size_t)B_ * TQ * UU;                 // 1 MB
    unsigned short* vht = (unsigned short*)(ek + (size_t)B_ * TV * UU);   // 2 MB
    unsigned short* vlt = vht + (size_t)B_ * DD * TV;                     // 2 MB
    unsigned short* wth = vlt + (size_t)B_ * DD * TV;                     // 256 KB
    unsigned short* wtl = wth + (size_t)2 * UU * DD;                      // 256 KB

    float* out  = (float*)d_out;
    float* ctx  = out;                                     // [B][TQ][DD]
    float* attn = out + (size_t)B_ * TQ * DD;              // [B][TQ][TV]

    split_kernel<<<288, 256, 0, stream>>>(value, W1, W2, vht, vlt, wth, wtl);
    projm_kernel<<<dim3((B_*TQ)/16, UU/64, 2), 256, 0, stream>>>(query, value, wth, wtl, eq, ek);
    fused_kernel<<<dim3(TQ/QB, B_), 1024, 0, stream>>>(eq, ek, scale, attn);
    ctx_kernel<<<dim3((B_*TQ)/32, DD/64), 256, 0, stream>>>(attn, vht, vlt, ctx);
}

// Round 18
// 68.096 us; speedup vs baseline: 1.5585x; 1.0147x over previous
//
#include <hip/hip_runtime.h>

#define B_  2
#define TQ  1024
#define TV  1024
#define DD  512
#define UU  128

#define QB  4            // q-rows per fused block

typedef __attribute__((ext_vector_type(8))) short short8;
typedef __attribute__((ext_vector_type(4))) float f32x4;

__device__ __forceinline__ unsigned short f2bf(float x){
    unsigned int u = __float_as_uint(x);
    unsigned int r = (u + 0x7FFFu + ((u >> 16) & 1u)) >> 16;
    return (unsigned short)r;
}
__device__ __forceinline__ float bf2f(unsigned short h){
    return __uint_as_float(((unsigned int)h) << 16);
}

// ---------------- W transpose + bf16 h/l split (tiny, runs first) ----------------
__global__ __launch_bounds__(256)
void wsplit_kernel(const float* __restrict__ W1, const float* __restrict__ W2,
                   unsigned short* __restrict__ wth, unsigned short* __restrict__ wtl){
    __shared__ float t[64][65];
    const int wb  = blockIdx.x;
    const int qk  = wb >> 4;
    const int rem = wb & 15;
    const int k0  = (rem >> 1) * 64;
    const int u0  = (rem & 1) * 64;
    const float* W = qk ? W2 : W1;
    const int tid = threadIdx.x;

    #pragma unroll
    for (int i = 0; i < 4; ++i){
        int r = (tid >> 4) + 16*i;
        int c = (tid & 15) * 4;
        float4 v = *reinterpret_cast<const float4*>(W + (size_t)(k0 + r)*UU + u0 + c);
        t[r][c+0]=v.x; t[r][c+1]=v.y; t[r][c+2]=v.z; t[r][c+3]=v.w;
    }
    __syncthreads();

    const int dr = tid >> 2;
    const int kc = (tid & 3) * 16;
    #pragma unroll
    for (int g = 0; g < 2; ++g){
        unsigned short h8[8], l8[8];
        #pragma unroll
        for (int e = 0; e < 8; ++e){
            float v = t[kc + g*8 + e][dr];
            unsigned short h = f2bf(v);
            h8[e] = h; l8[e] = f2bf(v - bf2f(h));
        }
        size_t o = ((size_t)qk*UU + u0 + dr)*(size_t)DD + k0 + kc + g*8;
        *reinterpret_cast<int4*>(wth + o) = *reinterpret_cast<const int4*>(h8);
        *reinterpret_cast<int4*>(wtl + o) = *reinterpret_cast<const int4*>(l8);
    }
}

// ---------------- merged: vsplit (blocks 0..255) + projm (blocks 256..767) ----------------
// vsplit: value [b][k][d] -> vht/vlt [b][d][k] bf16 planes
// projm : EQ/EK = exp2(C * X@W) via bf16-split MFMA (reads wth/wtl)
__global__ __launch_bounds__(256, 4)
void projv_kernel(const float* __restrict__ query, const float* __restrict__ value,
                  const unsigned short* __restrict__ wth, const unsigned short* __restrict__ wtl,
                  unsigned short* __restrict__ vht, unsigned short* __restrict__ vlt,
                  float* __restrict__ eq, float* __restrict__ ek){
    __shared__ char smem[20608];
    const int bid = blockIdx.x;
    const int tid = threadIdx.x;

    if (bid < 256){
        // ---- vsplit ----
        float (*t)[65] = reinterpret_cast<float(*)[65]>(smem);
        const int b   = bid >> 7;
        const int rem = bid & 127;
        const int k0  = (rem >> 3) * 64;
        const int d0  = (rem & 7) * 64;

        #pragma unroll
        for (int i = 0; i < 4; ++i){
            int r = (tid >> 4) + 16*i;
            int c = (tid & 15) * 4;
            float4 v = *reinterpret_cast<const float4*>(value + ((size_t)b*TV + k0 + r)*DD + d0 + c);
            t[r][c+0]=v.x; t[r][c+1]=v.y; t[r][c+2]=v.z; t[r][c+3]=v.w;
        }
        __syncthreads();

        const int dr = tid >> 2;
        const int kc = (tid & 3) * 16;
        #pragma unroll
        for (int g = 0; g < 2; ++g){
            unsigned short h8[8], l8[8];
            #pragma unroll
            for (int e = 0; e < 8; ++e){
                float v = t[kc + g*8 + e][dr];
                unsigned short h = f2bf(v);
                h8[e] = h; l8[e] = f2bf(v - bf2f(h));
            }
            size_t o = ((size_t)b*DD + d0 + dr)*(size_t)TV + k0 + kc + g*8;
            *reinterpret_cast<int4*>(vht + o) = *reinterpret_cast<const int4*>(h8);
            *reinterpret_cast<int4*>(vlt + o) = *reinterpret_cast<const int4*>(l8);
        }
        return;
    }

    // ---- projm ----
    unsigned short* Ah = reinterpret_cast<unsigned short*>(smem);            // 16*64
    unsigned short* Al = Ah + 16*64;                                          // 16*64
    unsigned short* Bh = Al + 16*64;                                          // 64*64
    unsigned short* Bl = Bh + 64*64;                                          // 64*64

    const float TWO_LOG2E = 2.8853900817779268f;
    const int pb  = bid - 256;               // 0..511
    const int qk  = pb >> 8;
    const int rem = pb & 255;
    const int r0g = (rem >> 1) * 16;
    const int n0  = (rem & 1) * 64;
    const float* X = qk ? value : query;
    float* out     = qk ? ek    : eq;
    const unsigned short* WH = wth + (size_t)qk * UU * DD;
    const unsigned short* WL = wtl + (size_t)qk * UU * DD;

    const int lane = tid & 63;
    const int w    = tid >> 6;

    const int ar  = tid >> 4;
    const int akq = (tid & 15) * 4;
    const int bc  = tid >> 2;
    const int bkc = (tid & 3) * 16;

    const float*          xrow  = X + (size_t)(r0g + ar) * DD;
    const unsigned short* whrow = WH + (size_t)(n0 + bc) * DD;
    const unsigned short* wlrow = WL + (size_t)(n0 + bc) * DD;

    float4 ra = *reinterpret_cast<const float4*>(xrow + akq);
    int4 rwh0 = *reinterpret_cast<const int4*>(whrow + bkc);
    int4 rwh1 = *reinterpret_cast<const int4*>(whrow + bkc + 8);
    int4 rwl0 = *reinterpret_cast<const int4*>(wlrow + bkc);
    int4 rwl1 = *reinterpret_cast<const int4*>(wlrow + bkc + 8);

    f32x4 acc = (f32x4){0.f,0.f,0.f,0.f};

    const int ga  = (akq >> 3) ^ (ar & 7);
    const int ao  = akq & 7;
    const int gb0 = ((bkc >> 3) + 0) ^ (bc & 7);
    const int gb1 = ((bkc >> 3) + 1) ^ (bc & 7);

    for (int kt = 0; kt < DD; kt += 64){
        {
            unsigned short h4[4], l4[4];
            #pragma unroll
            for (int e = 0; e < 4; ++e){
                float a = (e==0)?ra.x:(e==1)?ra.y:(e==2)?ra.z:ra.w;
                unsigned short h = f2bf(a);
                h4[e] = h; l4[e] = f2bf(a - bf2f(h));
            }
            *reinterpret_cast<int2*>(&Ah[ar*64 + ga*8 + ao]) = *reinterpret_cast<const int2*>(h4);
            *reinterpret_cast<int2*>(&Al[ar*64 + ga*8 + ao]) = *reinterpret_cast<const int2*>(l4);
        }
        *reinterpret_cast<int4*>(&Bh[bc*64 + gb0*8]) = rwh0;
        *reinterpret_cast<int4*>(&Bh[bc*64 + gb1*8]) = rwh1;
        *reinterpret_cast<int4*>(&Bl[bc*64 + gb0*8]) = rwl0;
        *reinterpret_cast<int4*>(&Bl[bc*64 + gb1*8]) = rwl1;

        const int ktn = (kt + 64 < DD) ? kt + 64 : 0;
        ra   = *reinterpret_cast<const float4*>(xrow + ktn + akq);
        rwh0 = *reinterpret_cast<const int4*>(whrow + ktn + bkc);
        rwh1 = *reinterpret_cast<const int4*>(whrow + ktn + bkc + 8);
        rwl0 = *reinterpret_cast<const int4*>(wlrow + ktn + bkc);
        rwl1 = *reinterpret_cast<const int4*>(wlrow + ktn + bkc + 8);

        __syncthreads();

        #pragma unroll
        for (int kk = 0; kk < 2; ++kk){
            const int kg = kk*4 + (lane >> 4);
            const int g  = (kg ^ (lane & 7)) * 8;
            const int r0 = (lane & 15) * 64;
            const int c0 = (w*16 + (lane & 15)) * 64;

            short8 ah = *reinterpret_cast<const short8*>(&Ah[r0 + g]);
            short8 al = *reinterpret_cast<const short8*>(&Al[r0 + g]);
            short8 bh = *reinterpret_cast<const short8*>(&Bh[c0 + g]);
            short8 bl = *reinterpret_cast<const short8*>(&Bl[c0 + g]);

            acc = __builtin_amdgcn_mfma_f32_16x16x32_bf16(ah, bh, acc, 0, 0, 0);
            acc = __builtin_amdgcn_mfma_f32_16x16x32_bf16(al, bh, acc, 0, 0, 0);
            acc = __builtin_amdgcn_mfma_f32_16x16x32_bf16(ah, bl, acc, 0, 0, 0);
        }

        __syncthreads();
    }

    const int orow = r0g + (lane >> 4) * 4;
    const int ocol = n0 + w*16 + (lane & 15);
    #pragma unroll
    for (int r = 0; r < 4; ++r)
        out[(size_t)(orow + r) * UU + ocol] = __builtin_amdgcn_exp2f(TWO_LOG2E * acc[r]);
}

// ---------------- fused scores + softmax (UNCHANGED from r17) ----------------
__global__ __launch_bounds__(1024, 8)
void fused_kernel(const float* __restrict__ eq, const float* __restrict__ ek,
                  const float* __restrict__ scale, float* __restrict__ attn){
    __shared__ float sm[QB][TV];
    __shared__ float psum[QB][4];

    const float LOG2E = 1.4426950408889634f;
    const int b   = blockIdx.y;
    const int q0  = blockIdx.x * QB;
    const int tid = threadIdx.x;
    const int w   = tid >> 6, lane = tid & 63;

    const float* qr0 = eq + ((size_t)b * TQ + q0 + 0) * UU;
    const float* qr1 = eq + ((size_t)b * TQ + q0 + 1) * UU;
    const float* qr2 = eq + ((size_t)b * TQ + q0 + 2) * UU;
    const float* qr3 = eq + ((size_t)b * TQ + q0 + 3) * UU;

    const float4* ekv = reinterpret_cast<const float4*>(ek + (size_t)b * TV * UU);

    const int kA = w*64 + lane;
    const size_t iA = (size_t)kA * 32;

    float acc[QB] = {};
    float4 kva = ekv[iA];

    for (int j = 0; j < 32; ++j){
        float4 nka;
        if (j != 31) nka = ekv[iA + j + 1];
        float4 s4 = *reinterpret_cast<const float4*>(scale + j*4);
        float4 q4;
        q4 = *reinterpret_cast<const float4*>(qr0 + j*4);
        acc[0] = fmaf(s4.x, __builtin_amdgcn_rcpf(fmaf(q4.x, kva.x, 1.0f)), acc[0]);
        acc[0] = fmaf(s4.y, __builtin_amdgcn_rcpf(fmaf(q4.y, kva.y, 1.0f)), acc[0]);
        acc[0] = fmaf(s4.z, __builtin_amdgcn_rcpf(fmaf(q4.z, kva.z, 1.0f)), acc[0]);
        acc[0] = fmaf(s4.w, __builtin_amdgcn_rcpf(fmaf(q4.w, kva.w, 1.0f)), acc[0]);
        q4 = *reinterpret_cast<const float4*>(qr1 + j*4);
        acc[1] = fmaf(s4.x, __builtin_amdgcn_rcpf(fmaf(q4.x, kva.x, 1.0f)), acc[1]);
        acc[1] = fmaf(s4.y, __builtin_amdgcn_rcpf(fmaf(q4.y, kva.y, 1.0f)), acc[1]);
        acc[1] = fmaf(s4.z, __builtin_amdgcn_rcpf(fmaf(q4.z, kva.z, 1.0f)), acc[1]);
        acc[1] = fmaf(s4.w, __builtin_amdgcn_rcpf(fmaf(q4.w, kva.w, 1.0f)), acc[1]);
        q4 = *reinterpret_cast<const float4*>(qr2 + j*4);
        acc[2] = fmaf(s4.x, __builtin_amdgcn_rcpf(fmaf(q4.x, kva.x, 1.0f)), acc[2]);
        acc[2] = fmaf(s4.y, __builtin_amdgcn_rcpf(fmaf(q4.y, kva.y, 1.0f)), acc[2]);
        acc[2] = fmaf(s4.z, __builtin_amdgcn_rcpf(fmaf(q4.z, kva.z, 1.0f)), acc[2]);
        acc[2] = fmaf(s4.w, __builtin_amdgcn_rcpf(fmaf(q4.w, kva.w, 1.0f)), acc[2]);
        q4 = *reinterpret_cast<const float4*>(qr3 + j*4);
        acc[3] = fmaf(s4.x, __builtin_amdgcn_rcpf(fmaf(q4.x, kva.x, 1.0f)), acc[3]);
        acc[3] = fmaf(s4.y, __builtin_amdgcn_rcpf(fmaf(q4.y, kva.y, 1.0f)), acc[3]);
        acc[3] = fmaf(s4.z, __builtin_amdgcn_rcpf(fmaf(q4.z, kva.z, 1.0f)), acc[3]);
        acc[3] = fmaf(s4.w, __builtin_amdgcn_rcpf(fmaf(q4.w, kva.w, 1.0f)), acc[3]);
        kva = nka;
    }

    #pragma unroll
    for (int r = 0; r < QB; ++r) sm[r][kA] = -2.0f * acc[r];
    __syncthreads();

    {
        const int r   = w & 3;
        const int seg = w >> 2;
        float s[4];
        #pragma unroll
        for (int t = 0; t < 4; ++t) s[t] = sm[r][seg*256 + t*64 + lane];

        float sum = 0.f;
        #pragma unroll
        for (int t = 0; t < 4; ++t){ s[t] = __builtin_amdgcn_exp2f(s[t] * LOG2E); sum += s[t]; }
        #pragma unroll
        for (int off = 32; off >= 1; off >>= 1) sum += __shfl_xor(sum, off, 64);
        if (lane == 0) psum[r][seg] = sum;
        __syncthreads();

        float S = (psum[r][0] + psum[r][1]) + (psum[r][2] + psum[r][3]);
        float inv = 1.0f / S;

        float* arow = attn + ((size_t)b * TQ + q0 + r) * TV + seg*256;
        #pragma unroll
        for (int t = 0; t < 4; ++t) arow[t*64 + lane] = s[t] * inv;
    }
}

// ---------------- context = attn @ value via bf16-split MFMA (UNCHANGED) ----------------
__global__ __launch_bounds__(256, 2)
void ctx_kernel(const float* __restrict__ attn,
                const unsigned short* __restrict__ vht, const unsigned short* __restrict__ vlt,
                float* __restrict__ ctx){
    __shared__ unsigned short Ah[32*64], Al[32*64], Vh[64*64], Vl[64*64];

    const int m0   = blockIdx.x * 32;
    const int n0   = blockIdx.y * 64;
    const int b    = m0 >> 10;
    const int tid  = threadIdx.x;
    const int lane = tid & 63;
    const int w    = tid >> 6;

    const int am = tid >> 3;
    const int kq = (tid & 7) * 8;
    const int cn = tid >> 2;
    const int kv = (tid & 3) * 16;

    const float*          arow  = attn + (size_t)(m0 + am) * TV;
    const unsigned short* vhrow = vht + ((size_t)b * DD + n0 + cn) * TV;
    const unsigned short* vlrow = vlt + ((size_t)b * DD + n0 + cn) * TV;

    float ra[8];
    int4 rvh0, rvh1, rvl0, rvl1;
    #pragma unroll
    for (int i = 0; i < 2; ++i)
        *reinterpret_cast<float4*>(&ra[i*4]) = *reinterpret_cast<const float4*>(arow + kq + i*4);
    rvh0 = *reinterpret_cast<const int4*>(vhrow + kv);
    rvh1 = *reinterpret_cast<const int4*>(vhrow + kv + 8);
    rvl0 = *reinterpret_cast<const int4*>(vlrow + kv);
    rvl1 = *reinterpret_cast<const int4*>(vlrow + kv + 8);

    f32x4 acc[2];
    acc[0] = (f32x4){0.f,0.f,0.f,0.f};
    acc[1] = (f32x4){0.f,0.f,0.f,0.f};

    const int ga  = (kq >> 3) ^ (am & 7);
    const int gv0 = ((kv >> 3) + 0) ^ (cn & 7);
    const int gv1 = ((kv >> 3) + 1) ^ (cn & 7);

    for (int kt = 0; kt < TV; kt += 64){
        {
            unsigned short h8[8], l8[8];
            #pragma unroll
            for (int e = 0; e < 8; ++e){
                float a = ra[e];
                unsigned short h = f2bf(a);
                h8[e] = h; l8[e] = f2bf(a - bf2f(h));
            }
            *reinterpret_cast<int4*>(&Ah[am*64 + ga*8]) = *reinterpret_cast<const int4*>(h8);
            *reinterpret_cast<int4*>(&Al[am*64 + ga*8]) = *reinterpret_cast<const int4*>(l8);
        }
        *reinterpret_cast<int4*>(&Vh[cn*64 + gv0*8]) = rvh0;
        *reinterpret_cast<int4*>(&Vh[cn*64 + gv1*8]) = rvh1;
        *reinterpret_cast<int4*>(&Vl[cn*64 + gv0*8]) = rvl0;
        *reinterpret_cast<int4*>(&Vl[cn*64 + gv1*8]) = rvl1;

        const int ktn = (kt + 64 < TV) ? kt + 64 : 0;
        #pragma unroll
        for (int i = 0; i < 2; ++i)
            *reinterpret_cast<float4*>(&ra[i*4]) = *reinterpret_cast<const float4*>(arow + ktn + kq + i*4);
        rvh0 = *reinterpret_cast<const int4*>(vhrow + ktn + kv);
        rvh1 = *reinterpret_cast<const int4*>(vhrow + ktn + kv + 8);
        rvl0 = *reinterpret_cast<const int4*>(vlrow + ktn + kv);
        rvl1 = *reinterpret_cast<const int4*>(vlrow + ktn + kv + 8);

        __syncthreads();

        #pragma unroll
        for (int kk = 0; kk < 2; ++kk){
            const int kg = kk*4 + (lane >> 4);
            const int g  = (kg ^ (lane & 7)) * 8;
            const int r0 = (lane & 15) * 64;
            const int c0 = (w*16 + (lane & 15)) * 64;

            short8 a0h = *reinterpret_cast<const short8*>(&Ah[r0 + g]);
            short8 a1h = *reinterpret_cast<const short8*>(&Ah[r0 + 16*64 + g]);
            short8 a0l = *reinterpret_cast<const short8*>(&Al[r0 + g]);
            short8 a1l = *reinterpret_cast<const short8*>(&Al[r0 + 16*64 + g]);
            short8 bh  = *reinterpret_cast<const short8*>(&Vh[c0 + g]);
            short8 bl  = *reinterpret_cast<const short8*>(&Vl[c0 + g]);

            acc[0] = __builtin_amdgcn_mfma_f32_16x16x32_bf16(a0h, bh, acc[0], 0, 0, 0);
            acc[0] = __builtin_amdgcn_mfma_f32_16x16x32_bf16(a0l, bh, acc[0], 0, 0, 0);
            acc[0] = __builtin_amdgcn_mfma_f32_16x16x32_bf16(a0h, bl, acc[0], 0, 0, 0);

            acc[1] = __builtin_amdgcn_mfma_f32_16x16x32_bf16(a1h, bh, acc[1], 0, 0, 0);
            acc[1] = __builtin_amdgcn_mfma_f32_16x16x32_bf16(a1l, bh, acc[1], 0, 0, 0);
            acc[1] = __builtin_amdgcn_mfma_f32_16x16x32_bf16(a1h, bl, acc[1], 0, 0, 0);
        }

        __syncthreads();
    }

    #pragma unroll
    for (int fm = 0; fm < 2; ++fm){
        const int row = m0 + fm*16 + (lane >> 4) * 4;
        const int col = n0 + w*16 + (lane & 15);
        #pragma unroll
        for (int r = 0; r < 4; ++r)
            ctx[(size_t)(row + r) * DD + col] = acc[fm][r];
    }
}

extern "C" void kernel_launch(void* const* d_in, const int* in_sizes, int n_in,
                              void* d_out, int out_size, void* d_ws, size_t ws_size,
                              hipStream_t stream){
    const float* query = (const float*)d_in[0];
    const float* value = (const float*)d_in[1];
    const float* W1    = (const float*)d_in[2];
    const float* W2    = (const float*)d_in[3];
    const float* scale = (const float*)d_in[4];

    float* eq = (float*)d_ws;                              // 1 MB
    float* ek = eq + (size_t)B_ * TQ * UU;                 // 1 MB
    unsigned short* vht = (unsigned short*)(ek + (size_t)B_ * TV * UU);   // 2 MB
    unsigned short* vlt = vht + (size_t)B_ * DD * TV;                     // 2 MB
    unsigned short* wth = vlt + (size_t)B_ * DD * TV;                     // 256 KB
    unsigned short* wtl = wth + (size_t)2 * UU * DD;                      // 256 KB

    float* out  = (float*)d_out;
    float* ctx  = out;                                     // [B][TQ][DD]
    float* attn = out + (size_t)B_ * TQ * DD;              // [B][TQ][TV]

    wsplit_kernel<<<32, 256, 0, stream>>>(W1, W2, wth, wtl);
    projv_kernel<<<768, 256, 0, stream>>>(query, value, wth, wtl, vht, vlt, eq, ek);
    fused_kernel<<<dim3(TQ/QB, B_), 1024, 0, stream>>>(eq, ek, scale, attn);
    ctx_kernel<<<dim3((B_*TQ)/32, DD/64), 256, 0, stream>>>(attn, vht, vlt, ctx);
}

// Round 21
// 64.938 us; speedup vs baseline: 1.6343x; 1.0486x over previous
//
#include <hip/hip_runtime.h>

#define B_  2
#define TQ  1024
#define TV  1024
#define DD  512
#define UU  128

#define QB  4            // q-rows per fused block

typedef __attribute__((ext_vector_type(8))) short short8;
typedef __attribute__((ext_vector_type(4))) float f32x4;
typedef __attribute__((ext_vector_type(2))) float f32x2;

__device__ __forceinline__ unsigned short f2bf(float x){
    unsigned int u = __float_as_uint(x);
    unsigned int r = (u + 0x7FFFu + ((u >> 16) & 1u)) >> 16;
    return (unsigned short)r;
}
__device__ __forceinline__ float bf2f(unsigned short h){
    return __uint_as_float(((unsigned int)h) << 16);
}

// ---------------- W transpose + bf16 h/l split (tiny, runs first) ----------------
__global__ __launch_bounds__(256)
void wsplit_kernel(const float* __restrict__ W1, const float* __restrict__ W2,
                   unsigned short* __restrict__ wth, unsigned short* __restrict__ wtl){
    __shared__ float t[64][65];
    const int wb  = blockIdx.x;
    const int qk  = wb >> 4;
    const int rem = wb & 15;
    const int k0  = (rem >> 1) * 64;
    const int u0  = (rem & 1) * 64;
    const float* W = qk ? W2 : W1;
    const int tid = threadIdx.x;

    #pragma unroll
    for (int i = 0; i < 4; ++i){
        int r = (tid >> 4) + 16*i;
        int c = (tid & 15) * 4;
        float4 v = *reinterpret_cast<const float4*>(W + (size_t)(k0 + r)*UU + u0 + c);
        t[r][c+0]=v.x; t[r][c+1]=v.y; t[r][c+2]=v.z; t[r][c+3]=v.w;
    }
    __syncthreads();

    const int dr = tid >> 2;
    const int kc = (tid & 3) * 16;
    #pragma unroll
    for (int g = 0; g < 2; ++g){
        unsigned short h8[8], l8[8];
        #pragma unroll
        for (int e = 0; e < 8; ++e){
            float v = t[kc + g*8 + e][dr];
            unsigned short h = f2bf(v);
            h8[e] = h; l8[e] = f2bf(v - bf2f(h));
        }
        size_t o = ((size_t)qk*UU + u0 + dr)*(size_t)DD + k0 + kc + g*8;
        *reinterpret_cast<int4*>(wth + o) = *reinterpret_cast<const int4*>(h8);
        *reinterpret_cast<int4*>(wtl + o) = *reinterpret_cast<const int4*>(l8);
    }
}

// ---------------- merged: vsplit (blocks 0..255) + projm (blocks 256..767) ----------------
__global__ __launch_bounds__(256, 4)
void projv_kernel(const float* __restrict__ query, const float* __restrict__ value,
                  const unsigned short* __restrict__ wth, const unsigned short* __restrict__ wtl,
                  unsigned short* __restrict__ vht, unsigned short* __restrict__ vlt,
                  float* __restrict__ eq, float* __restrict__ ek){
    __shared__ char smem[20608];
    const int bid = blockIdx.x;
    const int tid = threadIdx.x;

    if (bid < 256){
        // ---- vsplit ----
        float (*t)[65] = reinterpret_cast<float(*)[65]>(smem);
        const int b   = bid >> 7;
        const int rem = bid & 127;
        const int k0  = (rem >> 3) * 64;
        const int d0  = (rem & 7) * 64;

        #pragma unroll
        for (int i = 0; i < 4; ++i){
            int r = (tid >> 4) + 16*i;
            int c = (tid & 15) * 4;
            float4 v = *reinterpret_cast<const float4*>(value + ((size_t)b*TV + k0 + r)*DD + d0 + c);
            t[r][c+0]=v.x; t[r][c+1]=v.y; t[r][c+2]=v.z; t[r][c+3]=v.w;
        }
        __syncthreads();

        const int dr = tid >> 2;
        const int kc = (tid & 3) * 16;
        #pragma unroll
        for (int g = 0; g < 2; ++g){
            unsigned short h8[8], l8[8];
            #pragma unroll
            for (int e = 0; e < 8; ++e){
                float v = t[kc + g*8 + e][dr];
                unsigned short h = f2bf(v);
                h8[e] = h; l8[e] = f2bf(v - bf2f(h));
            }
            size_t o = ((size_t)b*DD + d0 + dr)*(size_t)TV + k0 + kc + g*8;
            *reinterpret_cast<int4*>(vht + o) = *reinterpret_cast<const int4*>(h8);
            *reinterpret_cast<int4*>(vlt + o) = *reinterpret_cast<const int4*>(l8);
        }
        return;
    }

    // ---- projm ----
    unsigned short* Ah = reinterpret_cast<unsigned short*>(smem);
    unsigned short* Al = Ah + 16*64;
    unsigned short* Bh = Al + 16*64;
    unsigned short* Bl = Bh + 64*64;

    const float TWO_LOG2E = 2.8853900817779268f;
    const int pb  = bid - 256;
    const int qk  = pb >> 8;
    const int rem = pb & 255;
    const int r0g = (rem >> 1) * 16;
    const int n0  = (rem & 1) * 64;
    const float* X = qk ? value : query;
    float* out     = qk ? ek    : eq;
    const unsigned short* WH = wth + (size_t)qk * UU * DD;
    const unsigned short* WL = wtl + (size_t)qk * UU * DD;

    const int lane = tid & 63;
    const int w    = tid >> 6;

    const int ar  = tid >> 4;
    const int akq = (tid & 15) * 4;
    const int bc  = tid >> 2;
    const int bkc = (tid & 3) * 16;

    const float*          xrow  = X + (size_t)(r0g + ar) * DD;
    const unsigned short* whrow = WH + (size_t)(n0 + bc) * DD;
    const unsigned short* wlrow = WL + (size_t)(n0 + bc) * DD;

    float4 ra = *reinterpret_cast<const float4*>(xrow + akq);
    int4 rwh0 = *reinterpret_cast<const int4*>(whrow + bkc);
    int4 rwh1 = *reinterpret_cast<const int4*>(whrow + bkc + 8);
    int4 rwl0 = *reinterpret_cast<const int4*>(wlrow + bkc);
    int4 rwl1 = *reinterpret_cast<const int4*>(wlrow + bkc + 8);

    f32x4 acc = (f32x4){0.f,0.f,0.f,0.f};

    const int ga  = (akq >> 3) ^ (ar & 7);
    const int ao  = akq & 7;
    const int gb0 = ((bkc >> 3) + 0) ^ (bc & 7);
    const int gb1 = ((bkc >> 3) + 1) ^ (bc & 7);

    for (int kt = 0; kt < DD; kt += 64){
        {
            unsigned short h4[4], l4[4];
            #pragma unroll
            for (int e = 0; e < 4; ++e){
                float a = (e==0)?ra.x:(e==1)?ra.y:(e==2)?ra.z:ra.w;
                unsigned short h = f2bf(a);
                h4[e] = h; l4[e] = f2bf(a - bf2f(h));
            }
            *reinterpret_cast<int2*>(&Ah[ar*64 + ga*8 + ao]) = *reinterpret_cast<const int2*>(h4);
            *reinterpret_cast<int2*>(&Al[ar*64 + ga*8 + ao]) = *reinterpret_cast<const int2*>(l4);
        }
        *reinterpret_cast<int4*>(&Bh[bc*64 + gb0*8]) = rwh0;
        *reinterpret_cast<int4*>(&Bh[bc*64 + gb1*8]) = rwh1;
        *reinterpret_cast<int4*>(&Bl[bc*64 + gb0*8]) = rwl0;
        *reinterpret_cast<int4*>(&Bl[bc*64 + gb1*8]) = rwl1;

        const int ktn = (kt + 64 < DD) ? kt + 64 : 0;
        ra   = *reinterpret_cast<const float4*>(xrow + ktn + akq);
        rwh0 = *reinterpret_cast<const int4*>(whrow + ktn + bkc);
        rwh1 = *reinterpret_cast<const int4*>(whrow + ktn + bkc + 8);
        rwl0 = *reinterpret_cast<const int4*>(wlrow + ktn + bkc);
        rwl1 = *reinterpret_cast<const int4*>(wlrow + ktn + bkc + 8);

        __syncthreads();

        #pragma unroll
        for (int kk = 0; kk < 2; ++kk){
            const int kg = kk*4 + (lane >> 4);
            const int g  = (kg ^ (lane & 7)) * 8;
            const int r0 = (lane & 15) * 64;
            const int c0 = (w*16 + (lane & 15)) * 64;

            short8 ah = *reinterpret_cast<const short8*>(&Ah[r0 + g]);
            short8 al = *reinterpret_cast<const short8*>(&Al[r0 + g]);
            short8 bh = *reinterpret_cast<const short8*>(&Bh[c0 + g]);
            short8 bl = *reinterpret_cast<const short8*>(&Bl[c0 + g]);

            acc = __builtin_amdgcn_mfma_f32_16x16x32_bf16(ah, bh, acc, 0, 0, 0);
            acc = __builtin_amdgcn_mfma_f32_16x16x32_bf16(al, bh, acc, 0, 0, 0);
            acc = __builtin_amdgcn_mfma_f32_16x16x32_bf16(ah, bl, acc, 0, 0, 0);
        }

        __syncthreads();
    }

    const int orow = r0g + (lane >> 4) * 4;
    const int ocol = n0 + w*16 + (lane & 15);
    #pragma unroll
    for (int r = 0; r < 4; ++r)
        out[(size_t)(orow + r) * UU + ocol] = __builtin_amdgcn_exp2f(TWO_LOG2E * acc[r]);
}

// ---------------- fused scores + softmax, packed f32x2 vector arithmetic ----------------
// score[q,k] = -2 * sum_u scale[u] * rcp(1 + EQ[q,u]*EK[k,u])  (+const, cancels in softmax)
// Packed math expressed as ext_vector C ops -> compiler emits v_pk_fma_f32 (or 2x v_fma_f32).
__global__ __launch_bounds__(1024, 8)
void fused_kernel(const float* __restrict__ eq, const float* __restrict__ ek,
                  const float* __restrict__ scale, float* __restrict__ attn){
    __shared__ float sm[QB][TV];
    __shared__ float psum[QB][4];

    const float LOG2E = 1.4426950408889634f;
    const int b   = blockIdx.y;
    const int q0  = blockIdx.x * QB;
    const int tid = threadIdx.x;
    const int w   = tid >> 6, lane = tid & 63;

    const f32x2* q0v = reinterpret_cast<const f32x2*>(eq + ((size_t)b * TQ + q0 + 0) * UU);
    const f32x2* q1v = reinterpret_cast<const f32x2*>(eq + ((size_t)b * TQ + q0 + 1) * UU);
    const f32x2* q2v = reinterpret_cast<const f32x2*>(eq + ((size_t)b * TQ + q0 + 2) * UU);
    const f32x2* q3v = reinterpret_cast<const f32x2*>(eq + ((size_t)b * TQ + q0 + 3) * UU);
    const f32x2* sc2 = reinterpret_cast<const f32x2*>(scale);

    const float4* ekv = reinterpret_cast<const float4*>(ek + (size_t)b * TV * UU);

    const int kA = w*64 + lane;
    const size_t iA = (size_t)kA * 32;

    f32x2 acc2[QB];
    #pragma unroll
    for (int r = 0; r < QB; ++r) acc2[r] = (f32x2){0.f, 0.f};
    const f32x2 one2 = (f32x2){1.0f, 1.0f};

    float4 kva = ekv[iA];

    for (int j = 0; j < 32; ++j){
        float4 nka;
        if (j != 31) nka = ekv[iA + j + 1];
        f32x2 sxy = sc2[2*j], szw = sc2[2*j+1];
        f32x2 kxy, kzw;
        kxy.x = kva.x; kxy.y = kva.y;
        kzw.x = kva.z; kzw.y = kva.w;
        #pragma unroll
        for (int r = 0; r < QB; ++r){
            const f32x2* qv = (r==0)?q0v:(r==1)?q1v:(r==2)?q2v:q3v;
            f32x2 q, t, rr;
            q = qv[2*j];
            t = q * kxy + one2;
            rr.x = __builtin_amdgcn_rcpf(t.x);
            rr.y = __builtin_amdgcn_rcpf(t.y);
            acc2[r] += sxy * rr;
            q = qv[2*j+1];
            t = q * kzw + one2;
            rr.x = __builtin_amdgcn_rcpf(t.x);
            rr.y = __builtin_amdgcn_rcpf(t.y);
            acc2[r] += szw * rr;
        }
        kva = nka;
    }

    #pragma unroll
    for (int r = 0; r < QB; ++r) sm[r][kA] = -2.0f * (acc2[r].x + acc2[r].y);
    __syncthreads();

    // no-max softmax: wave w -> row r = w&3, segment seg = w>>2 (256 k)
    {
        const int r   = w & 3;
        const int seg = w >> 2;
        float s[4];
        #pragma unroll
        for (int t = 0; t < 4; ++t) s[t] = sm[r][seg*256 + t*64 + lane];

        float sum = 0.f;
        #pragma unroll
        for (int t = 0; t < 4; ++t){ s[t] = __builtin_amdgcn_exp2f(s[t] * LOG2E); sum += s[t]; }
        #pragma unroll
        for (int off = 32; off >= 1; off >>= 1) sum += __shfl_xor(sum, off, 64);
        if (lane == 0) psum[r][seg] = sum;
        __syncthreads();

        float S = (psum[r][0] + psum[r][1]) + (psum[r][2] + psum[r][3]);
        float inv = 1.0f / S;

        float* arow = attn + ((size_t)b * TQ + q0 + r) * TV + seg*256;
        #pragma unroll
        for (int t = 0; t < 4; ++t) arow[t*64 + lane] = s[t] * inv;
    }
}

// ---------------- context = attn @ value via bf16-split MFMA (UNCHANGED) ----------------
__global__ __launch_bounds__(256, 2)
void ctx_kernel(const float* __restrict__ attn,
                const unsigned short* __restrict__ vht, const unsigned short* __restrict__ vlt,
                float* __restrict__ ctx){
    __shared__ unsigned short Ah[32*64], Al[32*64], Vh[64*64], Vl[64*64];

    const int m0   = blockIdx.x * 32;
    const int n0   = blockIdx.y * 64;
    const int b    = m0 >> 10;
    const int tid  = threadIdx.x;
    const int lane = tid & 63;
    const int w    = tid >> 6;

    const int am = tid >> 3;
    const int kq = (tid & 7) * 8;
    const int cn = tid >> 2;
    const int kv = (tid & 3) * 16;

    const float*          arow  = attn + (size_t)(m0 + am) * TV;
    const unsigned short* vhrow = vht + ((size_t)b * DD + n0 + cn) * TV;
    const unsigned short* vlrow = vlt + ((size_t)b * DD + n0 + cn) * TV;

    float ra[8];
    int4 rvh0, rvh1, rvl0, rvl1;
    #pragma unroll
    for (int i = 0; i < 2; ++i)
        *reinterpret_cast<float4*>(&ra[i*4]) = *reinterpret_cast<const float4*>(arow + kq + i*4);
    rvh0 = *reinterpret_cast<const int4*>(vhrow + kv);
    rvh1 = *reinterpret_cast<const int4*>(vhrow + kv + 8);
    rvl0 = *reinterpret_cast<const int4*>(vlrow + kv);
    rvl1 = *reinterpret_cast<const int4*>(vlrow + kv + 8);

    f32x4 acc[2];
    acc[0] = (f32x4){0.f,0.f,0.f,0.f};
    acc[1] = (f32x4){0.f,0.f,0.f,0.f};

    const int ga  = (kq >> 3) ^ (am & 7);
    const int gv0 = ((kv >> 3) + 0) ^ (cn & 7);
    const int gv1 = ((kv >> 3) + 1) ^ (cn & 7);

    for (int kt = 0; kt < TV; kt += 64){
        {
            unsigned short h8[8], l8[8];
            #pragma unroll
            for (int e = 0; e < 8; ++e){
                float a = ra[e];
                unsigned short h = f2bf(a);
                h8[e] = h; l8[e] = f2bf(a - bf2f(h));
            }
            *reinterpret_cast<int4*>(&Ah[am*64 + ga*8]) = *reinterpret_cast<const int4*>(h8);
            *reinterpret_cast<int4*>(&Al[am*64 + ga*8]) = *reinterpret_cast<const int4*>(l8);
        }
        *reinterpret_cast<int4*>(&Vh[cn*64 + gv0*8]) = rvh0;
        *reinterpret_cast<int4*>(&Vh[cn*64 + gv1*8]) = rvh1;
        *reinterpret_cast<int4*>(&Vl[cn*64 + gv0*8]) = rvl0;
        *reinterpret_cast<int4*>(&Vl[cn*64 + gv1*8]) = rvl1;

        const int ktn = (kt + 64 < TV) ? kt + 64 : 0;
        #pragma unroll
        for (int i = 0; i < 2; ++i)
            *reinterpret_cast<float4*>(&ra[i*4]) = *reinterpret_cast<const float4*>(arow + ktn + kq + i*4);
        rvh0 = *reinterpret_cast<const int4*>(vhrow + ktn + kv);
        rvh1 = *reinterpret_cast<const int4*>(vhrow + ktn + kv + 8);
        rvl0 = *reinterpret_cast<const int4*>(vlrow + ktn + kv);
        rvl1 = *reinterpret_cast<const int4*>(vlrow + ktn + kv + 8);

        __syncthreads();

        #pragma unroll
        for (int kk = 0; kk < 2; ++kk){
            const int kg = kk*4 + (lane >> 4);
            const int g  = (kg ^ (lane & 7)) * 8;
            const int r0 = (lane & 15) * 64;
            const int c0 = (w*16 + (lane & 15)) * 64;

            short8 a0h = *reinterpret_cast<const short8*>(&Ah[r0 + g]);
            short8 a1h = *reinterpret_cast<const short8*>(&Ah[r0 + 16*64 + g]);
            short8 a0l = *reinterpret_cast<const short8*>(&Al[r0 + g]);
            short8 a1l = *reinterpret_cast<const short8*>(&Al[r0 + 16*64 + g]);
            short8 bh  = *reinterpret_cast<const short8*>(&Vh[c0 + g]);
            short8 bl  = *reinterpret_cast<const short8*>(&Vl[c0 + g]);

            acc[0] = __builtin_amdgcn_mfma_f32_16x16x32_bf16(a0h, bh, acc[0], 0, 0, 0);
            acc[0] = __builtin_amdgcn_mfma_f32_16x16x32_bf16(a0l, bh, acc[0], 0, 0, 0);
            acc[0] = __builtin_amdgcn_mfma_f32_16x16x32_bf16(a0h, bl, acc[0], 0, 0, 0);

            acc[1] = __builtin_amdgcn_mfma_f32_16x16x32_bf16(a1h, bh, acc[1], 0, 0, 0);
            acc[1] = __builtin_amdgcn_mfma_f32_16x16x32_bf16(a1l, bh, acc[1], 0, 0, 0);
            acc[1] = __builtin_amdgcn_mfma_f32_16x16x32_bf16(a1h, bl, acc[1], 0, 0, 0);
        }

        __syncthreads();
    }

    #pragma unroll
    for (int fm = 0; fm < 2; ++fm){
        const int row = m0 + fm*16 + (lane >> 4) * 4;
        const int col = n0 + w*16 + (lane & 15);
        #pragma unroll
        for (int r = 0; r < 4; ++r)
            ctx[(size_t)(row + r) * DD + col] = acc[fm][r];
    }
}

extern "C" void kernel_launch(void* const* d_in, const int* in_sizes, int n_in,
                              void* d_out, int out_size, void* d_ws, size_t ws_size,
                              hipStream_t stream){
    const float* query = (const float*)d_in[0];
    const float* value = (const float*)d_in[1];
    const float* W1    = (const float*)d_in[2];
    const float* W2    = (const float*)d_in[3];
    const float* scale = (const float*)d_in[4];

    float* eq = (float*)d_ws;                              // 1 MB
    float* ek = eq + (size_t)B_ * TQ * UU;                 // 1 MB
    unsigned short* vht = (unsigned short*)(ek + (size_t)B_ * TV * UU);   // 2 MB
    unsigned short* vlt = vht + (size_t)B_ * DD * TV;                     // 2 MB
    unsigned short* wth = vlt + (size_t)B_ * DD * TV;                     // 256 KB
    unsigned short* wtl = wth + (size_t)2 * UU * DD;                      // 256 KB

    float* out  = (float*)d_out;
    float* ctx  = out;                                     // [B][TQ][DD]
    float* attn = out + (size_t)B_ * TQ * DD;              // [B][TQ][TV]

    wsplit_kernel<<<32, 256, 0, stream>>>(W1, W2, wth, wtl);
    projv_kernel<<<768, 256, 0, stream>>>(query, value, wth, wtl, vht, vlt, eq, ek);
    fused_kernel<<<dim3(TQ/QB, B_), 1024, 0, stream>>>(eq, ek, scale, attn);
    ctx_kernel<<<dim3((B_*TQ)/32, DD/64), 256, 0, stream>>>(attn, vht, vlt, ctx);
}